// Round 4
// baseline (2952.326 us; speedup 1.0000x reference)
//
#include <hip/hip_runtime.h>
#include <math.h>

typedef unsigned short ushort_t;

constexpr int B_ = 64, S_ = 512, DIM_ = 1024, COV_ = 256, TC_ = 768, KIH_ = 2049;

__device__ __forceinline__ float b2f(ushort_t u) {
    union { unsigned int i; float f; } v; v.i = ((unsigned int)u) << 16; return v.f;
}
__device__ __forceinline__ ushort_t f2b(float f) {
    unsigned int x = __float_as_uint(f);
    unsigned int r = x + 0x7fffu + ((x >> 16) & 1u);
    return (ushort_t)(r >> 16);
}
__device__ __forceinline__ float ldv(const float* p, size_t i) { return p[i]; }
__device__ __forceinline__ float ldv(const ushort_t* p, size_t i) { return b2f(p[i]); }

__device__ __forceinline__ float wave_reduce(float a) {
#pragma unroll
    for (int off = 32; off >= 1; off >>= 1) a += __shfl_down(a, off, 64);
    return a;
}

// ---- dtype detection: flags[0]=mask_is_bytes, flags[1]=inputs_are_f32 ---------
__global__ void k_detect(const unsigned char* __restrict__ mask,
                         const ushort_t* __restrict__ win,
                         int* __restrict__ flags) {
    __shared__ int red0[256];
    __shared__ int red1[256];
    int tid = threadIdx.x, mb = 0, f32 = 0;
    for (int i = tid; i < 32768; i += 256)
        if ((i & 3) != 0 && mask[i] != 0) mb = 1;
    for (int i = tid; i < 32768; i += 256) {
        ushort_t u = win[2 * i];
        if ((u & 0x7F80u) >= 0x4480u) f32 = 1;
    }
    red0[tid] = mb; red1[tid] = f32; __syncthreads();
    for (int st = 128; st >= 1; st >>= 1) {
        if (tid < st) { red0[tid] |= red0[tid + st]; red1[tid] |= red1[tid + st]; }
        __syncthreads();
    }
    if (tid == 0) { flags[0] = red0[0]; flags[1] = red1[0]; }
}

// ---- generic transpose -> canonical bf16: out[c*R+r] = in[r*ld+off+c] ---------
template <typename IT>
__device__ __forceinline__ void transpose_body(const IT* __restrict__ in,
                                               ushort_t* __restrict__ out,
                                               int R, int C, int ld, int off) {
    int idx = blockIdx.x * 256 + threadIdx.x;
    if (idx >= R * C) return;
    int r = idx / C, c = idx - r * C;
    out[c * R + r] = f2b(ldv(in, (size_t)r * ld + off + c));
}
__global__ void k_transpose(const void* __restrict__ in, ushort_t* __restrict__ out,
                            int R, int C, int ld, int off, const int* __restrict__ flags) {
    if (flags[1]) transpose_body((const float*)in, out, R, C, ld, off);
    else transpose_body((const ushort_t*)in, out, R, C, ld, off);
}

// ---- watt[j] = w_ih[j, 2048] --------------------------------------------------
template <typename IT>
__device__ __forceinline__ void watt_body(const IT* __restrict__ wih, float* __restrict__ watt) {
    int j = threadIdx.x;  // 768 threads
    watt[j] = ldv(wih, (size_t)j * KIH_ + 2048);
}
__global__ void k_watt(const void* __restrict__ wih, float* __restrict__ watt,
                       const int* __restrict__ flags) {
    if (flags[1]) watt_body((const float*)wih, watt);
    else watt_body((const ushort_t*)wih, watt);
}

// ---- bfold[j] = sum_d bcov[d] * w_ih[j, d] ------------------------------------
template <typename IT>
__device__ __forceinline__ void bfold_body(const IT* __restrict__ bcov,
                                           const IT* __restrict__ wih,
                                           float* __restrict__ bfold) {
    int j = blockIdx.x * 4 + (threadIdx.x >> 6);
    int lane = threadIdx.x & 63;
    const IT* wr = wih + (size_t)j * KIH_;
    float a = 0.f;
#pragma unroll
    for (int i = 0; i < 16; ++i) { int k = lane + 64 * i; a += ldv(bcov, k) * ldv(wr, k); }
    a = wave_reduce(a);
    if (lane == 0) bfold[j] = a;
}
__global__ __launch_bounds__(256) void k_bfold(const void* __restrict__ bcov,
                                               const void* __restrict__ wih,
                                               float* __restrict__ bfold,
                                               const int* __restrict__ flags) {
    if (flags[1]) bfold_body((const float*)bcov, (const float*)wih, bfold);
    else bfold_body((const ushort_t*)bcov, (const ushort_t*)wih, bfold);
}

// ---- wfold[c*768+j] = sum_d W_cov[d,c] * w_ih[j,d]  (canonical inputs) --------
__global__ __launch_bounds__(256) void k_wfold(const ushort_t* __restrict__ wcov_t,
                                               const ushort_t* __restrict__ w_t,
                                               float* __restrict__ wfold) {
    __shared__ float col[DIM_];
    int c = blockIdx.x, tid = threadIdx.x;
    for (int d = tid; d < DIM_; d += 256) col[d] = b2f(wcov_t[c * DIM_ + d]);
    __syncthreads();
    float a0 = 0.f, a1 = 0.f, a2 = 0.f;
    for (int d = 0; d < DIM_; ++d) {
        float x = col[d];
        const ushort_t* wr = w_t + d * TC_;
        a0 += x * b2f(wr[tid]);
        a1 += x * b2f(wr[tid + 256]);
        a2 += x * b2f(wr[tid + 512]);
    }
    wfold[c * TC_ + tid] = a0;
    wfold[c * TC_ + tid + 256] = a1;
    wfold[c * TC_ + tid + 512] = a2;
}

// ---- target = h @ W_in^T (wave per output) ------------------------------------
template <typename IT>
__device__ __forceinline__ void target_body(const IT* __restrict__ h,
                                            const IT* __restrict__ W_in,
                                            float* __restrict__ target) {
    int o = blockIdx.x * 4 + (threadIdx.x >> 6);
    int lane = threadIdx.x & 63;
    int b = o >> 10, d = o & (DIM_ - 1);
    const IT* hr = h + (size_t)b * DIM_;
    const IT* wr = W_in + (size_t)d * DIM_;
    float a = 0.f;
#pragma unroll
    for (int j = 0; j < 16; ++j) { int k = lane + 64 * j; a += ldv(hr, k) * ldv(wr, k); }
    a = wave_reduce(a);
    if (lane == 0) target[o] = a;
}
__global__ __launch_bounds__(256) void k_target_w(const void* __restrict__ h,
                                                  const void* __restrict__ W_in,
                                                  float* __restrict__ target,
                                                  const int* __restrict__ flags) {
    if (flags[1]) target_body((const float*)h, (const float*)W_in, target);
    else target_body((const ushort_t*)h, (const ushort_t*)W_in, target);
}

// ---- mvec[b,c] = sum_d target[b,d]*W_cov[d,c];  bct[b] = sum_d target*b_cov ---
template <typename IT>
__device__ __forceinline__ void mvec_body(const float* __restrict__ target,
                                          const IT* __restrict__ W_cov,
                                          const IT* __restrict__ bcov,
                                          float* __restrict__ mvec,
                                          float* __restrict__ bct) {
    __shared__ float tg[DIM_];
    __shared__ float red[256];
    int b = blockIdx.x, tid = threadIdx.x;
    float pb = 0.f;
    for (int k = tid; k < DIM_; k += 256) {
        float t = target[b * DIM_ + k];
        tg[k] = t; pb += t * ldv(bcov, k);
    }
    red[tid] = pb; __syncthreads();
    for (int st = 128; st >= 1; st >>= 1) {
        if (tid < st) red[tid] += red[tid + st];
        __syncthreads();
    }
    float acc = 0.f;
    for (int d = 0; d < DIM_; ++d) acc += tg[d] * ldv(W_cov, (size_t)d * COV_ + tid);
    mvec[b * COV_ + tid] = acc;
    if (tid == 0) bct[b] = red[0];
}
__global__ __launch_bounds__(256) void k_mvec(const float* __restrict__ target,
                                              const void* __restrict__ W_cov,
                                              const void* __restrict__ bcov,
                                              float* __restrict__ mvec,
                                              float* __restrict__ bct,
                                              const int* __restrict__ flags) {
    if (flags[1]) mvec_body(target, (const float*)W_cov, (const float*)bcov, mvec, bct);
    else mvec_body(target, (const ushort_t*)W_cov, (const ushort_t*)bcov, mvec, bct);
}

// ---- scores + masked softmax --------------------------------------------------
template <typename IT>
__device__ __forceinline__ void scores_body(const IT* __restrict__ context,
                                            const IT* __restrict__ cov,
                                            const float* __restrict__ target,
                                            const float* __restrict__ mvec,
                                            const float* __restrict__ bct,
                                            const void* __restrict__ maskp,
                                            int mask_bytes,
                                            float* __restrict__ attnf,
                                            float* __restrict__ attn_out) {
    __shared__ float tg[DIM_];
    __shared__ float ms[COV_];
    __shared__ float sc[S_];
    __shared__ float red[256];
    int b = blockIdx.x, tid = threadIdx.x;
    for (int k = tid; k < DIM_; k += 256) tg[k] = target[b * DIM_ + k];
    ms[tid] = mvec[b * COV_ + tid];
    float bc = bct[b];
    __syncthreads();
    int wave = tid >> 6, lane = tid & 63;
    for (int s = wave; s < S_; s += 4) {
        size_t row = (size_t)(b * S_ + s);
        const IT* cr = context + row * DIM_;
        const IT* vr = cov + row * COV_;
        float a = 0.f;
#pragma unroll
        for (int j = 0; j < 16; ++j) { int d = lane + 64 * j; a += ldv(cr, d) * tg[d]; }
#pragma unroll
        for (int j = 0; j < 4; ++j) { int c = lane + 64 * j; a += ldv(vr, c) * ms[c]; }
        a = wave_reduce(a);
        if (lane == 0) {
            int idx = b * S_ + s;
            int mval = mask_bytes ? (int)((const unsigned char*)maskp)[idx]
                                  : ((const int*)maskp)[idx];
            sc[s] = mval ? -INFINITY : (a + bc);
        }
    }
    __syncthreads();
    float m0 = fmaxf(sc[tid], sc[tid + 256]);
    red[tid] = m0; __syncthreads();
    for (int st = 128; st >= 1; st >>= 1) {
        if (tid < st) red[tid] = fmaxf(red[tid], red[tid + st]);
        __syncthreads();
    }
    float mx = red[0]; __syncthreads();
    float e0 = expf(sc[tid] - mx), e1 = expf(sc[tid + 256] - mx);
    red[tid] = e0 + e1; __syncthreads();
    for (int st = 128; st >= 1; st >>= 1) {
        if (tid < st) red[tid] += red[tid + st];
        __syncthreads();
    }
    float inv = 1.0f / red[0];
    float a0 = e0 * inv, a1 = e1 * inv;
    attnf[b * S_ + tid] = a0; attnf[b * S_ + tid + 256] = a1;
    attn_out[b * S_ + tid] = a0; attn_out[b * S_ + tid + 256] = a1;
}
__global__ __launch_bounds__(256) void k_scores_f(const void* __restrict__ context,
                                                  const void* __restrict__ cov,
                                                  const float* __restrict__ target,
                                                  const float* __restrict__ mvec,
                                                  const float* __restrict__ bct,
                                                  const void* __restrict__ maskp,
                                                  const int* __restrict__ flags,
                                                  float* __restrict__ attnf,
                                                  float* __restrict__ attn_out) {
    int mb = flags[0];
    if (flags[1]) scores_body((const float*)context, (const float*)cov, target, mvec,
                              bct, maskp, mb, attnf, attn_out);
    else scores_body((const ushort_t*)context, (const ushort_t*)cov, target, mvec,
                     bct, maskp, mb, attnf, attn_out);
}

// ---- wc = attn@context + (attn@cov)@W_cov^T + b_cov ---------------------------
template <typename IT>
__device__ __forceinline__ void wc_body(const IT* __restrict__ context,
                                        const IT* __restrict__ cov,
                                        const ushort_t* __restrict__ wcov_t,
                                        const IT* __restrict__ bcov,
                                        const float* __restrict__ attnf,
                                        float* __restrict__ wc) {
    __shared__ float at[S_];
    __shared__ float ac[COV_];
    int b = blockIdx.x, tid = threadIdx.x;
    at[tid] = attnf[b * S_ + tid];
    at[tid + 256] = attnf[b * S_ + tid + 256];
    __syncthreads();
    float a = 0.f;
    for (int s = 0; s < S_; ++s) a += at[s] * ldv(cov, ((size_t)(b * S_ + s)) * COV_ + tid);
    ac[tid] = a;
    __syncthreads();
    float acc[4] = {0.f, 0.f, 0.f, 0.f};
    for (int s = 0; s < S_; ++s) {
        float w = at[s];
        const IT* cr = context + ((size_t)(b * S_ + s)) * DIM_;
        acc[0] += w * ldv(cr, tid);
        acc[1] += w * ldv(cr, tid + 256);
        acc[2] += w * ldv(cr, tid + 512);
        acc[3] += w * ldv(cr, tid + 768);
    }
    for (int c = 0; c < COV_; ++c) {
        float av = ac[c];
        const ushort_t* wr = wcov_t + c * DIM_;
        acc[0] += av * b2f(wr[tid]);
        acc[1] += av * b2f(wr[tid + 256]);
        acc[2] += av * b2f(wr[tid + 512]);
        acc[3] += av * b2f(wr[tid + 768]);
    }
    for (int m = 0; m < 4; ++m) {
        int d = tid + 256 * m;
        wc[b * DIM_ + d] = acc[m] + ldv(bcov, d);
    }
}
__global__ __launch_bounds__(256) void k_wc_f(const void* __restrict__ context,
                                              const void* __restrict__ cov,
                                              const ushort_t* __restrict__ wcov_t,
                                              const void* __restrict__ bcov,
                                              const float* __restrict__ attnf,
                                              float* __restrict__ wc,
                                              const int* __restrict__ flags) {
    if (flags[1]) wc_body((const float*)context, (const float*)cov, wcov_t,
                          (const float*)bcov, attnf, wc);
    else wc_body((const ushort_t*)context, (const ushort_t*)cov, wcov_t,
                 (const ushort_t*)bcov, attnf, wc);
}

// ---- h_tilde = tanh([wc, h] @ W_out^T) (wave per output) ----------------------
template <typename IT>
__device__ __forceinline__ void htilde_body(const float* __restrict__ wc,
                                            const IT* __restrict__ h,
                                            const IT* __restrict__ W_out,
                                            float* __restrict__ out_ht) {
    int o = blockIdx.x * 4 + (threadIdx.x >> 6);
    int lane = threadIdx.x & 63;
    int b = o >> 10, d = o & (DIM_ - 1);
    const float* wcr = wc + b * DIM_;
    const IT* hr = h + (size_t)b * DIM_;
    const IT* wr = W_out + (size_t)d * 2 * DIM_;
    float a = 0.f;
#pragma unroll
    for (int j = 0; j < 16; ++j) { int k = lane + 64 * j; a += wcr[k] * ldv(wr, k); }
#pragma unroll
    for (int j = 0; j < 16; ++j) { int k = lane + 64 * j; a += ldv(hr, k) * ldv(wr, DIM_ + k); }
    a = wave_reduce(a);
    if (lane == 0) out_ht[o] = tanhf(a);
}
__global__ __launch_bounds__(256) void k_htilde_w(const float* __restrict__ wc,
                                                  const void* __restrict__ h,
                                                  const void* __restrict__ W_out,
                                                  float* __restrict__ out_ht,
                                                  const int* __restrict__ flags) {
    if (flags[1]) htilde_body(wc, (const float*)h, (const float*)W_out, out_ht);
    else htilde_body(wc, (const ushort_t*)h, (const ushort_t*)W_out, out_ht);
}

// ---- gxall[b,j] = b_ih[j] + bfold[j] + sum_k h[b,k]*w_ih[j,1024+k] ------------
template <typename IT>
__device__ __forceinline__ void gxh_body(const IT* __restrict__ h,
                                         const IT* __restrict__ w_ih,
                                         const IT* __restrict__ b_ih,
                                         const float* __restrict__ bfold,
                                         float* __restrict__ gxall) {
    int o = blockIdx.x * 4 + (threadIdx.x >> 6);
    int lane = threadIdx.x & 63;
    int b = o / TC_, j = o - b * TC_;
    const IT* hr = h + (size_t)b * DIM_;
    const IT* wr = w_ih + (size_t)j * KIH_ + DIM_;
    float a = 0.f;
#pragma unroll
    for (int i = 0; i < 16; ++i) { int k = lane + 64 * i; a += ldv(hr, k) * ldv(wr, k); }
    a = wave_reduce(a);
    if (lane == 0) gxall[o] = a + ldv(b_ih, j) + bfold[j];
}
__global__ __launch_bounds__(256) void k_gxh_w(const void* __restrict__ h,
                                               const void* __restrict__ w_ih,
                                               const void* __restrict__ b_ih,
                                               const float* __restrict__ bfold,
                                               float* __restrict__ gxall,
                                               const int* __restrict__ flags) {
    if (flags[1]) gxh_body((const float*)h, (const float*)w_ih, (const float*)b_ih, bfold, gxall);
    else gxh_body((const ushort_t*)h, (const ushort_t*)w_ih, (const ushort_t*)b_ih, bfold, gxall);
}

// ---- GRU coverage update ------------------------------------------------------
template <typename IT>
__device__ __forceinline__ void gru_body(const IT* __restrict__ context,
                                         const IT* __restrict__ cov,
                                         const float* __restrict__ attnf,
                                         const float* __restrict__ gxall,
                                         const float* __restrict__ watt,
                                         const ushort_t* __restrict__ w_t,
                                         const float* __restrict__ wfold,
                                         const ushort_t* __restrict__ whh_t,
                                         const IT* __restrict__ bhh,
                                         float* __restrict__ out_cov) {
    __shared__ float xc[8][DIM_];
    __shared__ float h0s[8][COV_];
    __shared__ float atn[8];
    int base = blockIdx.x * 8, tid = threadIdx.x;
    int b = base / S_;  // 8 rows share b (512 % 8 == 0)
    for (int i = tid; i < 8 * DIM_; i += 256)
        ((float*)xc)[i] = ldv(context, (size_t)base * DIM_ + i);
    for (int i = tid; i < 8 * COV_; i += 256)
        ((float*)h0s)[i] = ldv(cov, (size_t)base * COV_ + i);
    if (tid < 8) atn[tid] = attnf[base + tid];
    __syncthreads();
    int c = tid;
    float gxR = gxall[b * TC_ + c], gxZ = gxall[b * TC_ + 256 + c], gxN = gxall[b * TC_ + 512 + c];
    float bhR = ldv(bhh, c), bhZ = ldv(bhh, 256 + c), bhN = ldv(bhh, 512 + c);
    float waR = watt[c], waZ = watt[256 + c], waN = watt[512 + c];
    float aR[8], aZ[8], aXN[8], aHN[8];
#pragma unroll
    for (int g = 0; g < 8; ++g) {
        float a = atn[g];
        aR[g] = gxR + bhR + a * waR;
        aZ[g] = gxZ + bhZ + a * waZ;
        aXN[g] = gxN + a * waN;
        aHN[g] = bhN;
    }
    for (int k = 0; k < DIM_; ++k) {
        const ushort_t* row = w_t + k * TC_;
        float wr = b2f(row[c]), wz = b2f(row[256 + c]), wn = b2f(row[512 + c]);
#pragma unroll
        for (int g = 0; g < 8; ++g) {
            float x = xc[g][k];
            aR[g] += x * wr; aZ[g] += x * wz; aXN[g] += x * wn;
        }
    }
    for (int k = 0; k < COV_; ++k) {
        const float* row = wfold + k * TC_;
        float wr = row[c], wz = row[256 + c], wn = row[512 + c];
#pragma unroll
        for (int g = 0; g < 8; ++g) {
            float x = h0s[g][k];
            aR[g] += x * wr; aZ[g] += x * wz; aXN[g] += x * wn;
        }
    }
    for (int k = 0; k < COV_; ++k) {
        const ushort_t* row = whh_t + k * TC_;
        float wr = b2f(row[c]), wz = b2f(row[256 + c]), wn = b2f(row[512 + c]);
#pragma unroll
        for (int g = 0; g < 8; ++g) {
            float hh = h0s[g][k];
            aR[g] += hh * wr; aZ[g] += hh * wz; aHN[g] += hh * wn;
        }
    }
#pragma unroll
    for (int g = 0; g < 8; ++g) {
        float r = 1.f / (1.f + expf(-aR[g]));
        float z = 1.f / (1.f + expf(-aZ[g]));
        float n = tanhf(aXN[g] + r * aHN[g]);
        float h0c = h0s[g][c];
        out_cov[(size_t)(base + g) * COV_ + c] = (1.f - z) * n + z * h0c;
    }
}
__global__ __launch_bounds__(256) void k_gru_f(const void* __restrict__ context,
                                               const void* __restrict__ cov,
                                               const float* __restrict__ attnf,
                                               const float* __restrict__ gxall,
                                               const float* __restrict__ watt,
                                               const ushort_t* __restrict__ w_t,
                                               const float* __restrict__ wfold,
                                               const ushort_t* __restrict__ whh_t,
                                               const void* __restrict__ bhh,
                                               float* __restrict__ out_cov,
                                               const int* __restrict__ flags) {
    if (flags[1]) gru_body((const float*)context, (const float*)cov, attnf, gxall, watt,
                           w_t, wfold, whh_t, (const float*)bhh, out_cov);
    else gru_body((const ushort_t*)context, (const ushort_t*)cov, attnf, gxall, watt,
                  w_t, wfold, whh_t, (const ushort_t*)bhh, out_cov);
}

extern "C" void kernel_launch(void* const* d_in, const int* in_sizes, int n_in,
                              void* d_out, int out_size, void* d_ws, size_t ws_size,
                              hipStream_t stream) {
    const void* h       = d_in[0];
    const void* context = d_in[1];
    const void* cov     = d_in[2];
    const void* W_in    = d_in[3];
    const void* W_out   = d_in[4];
    const void* W_cov   = d_in[5];
    const void* b_cov   = d_in[6];
    const void* w_ih    = d_in[7];
    const void* w_hh    = d_in[8];
    const void* b_ih    = d_in[9];
    const void* b_hh    = d_in[10];
    const void* maskp   = d_in[11];

    float* out = (float*)d_out;           // reference output dtype is float32
    float* out_ht   = out;
    float* out_attn = out + B_ * DIM_;
    float* out_cov  = out + B_ * DIM_ + B_ * S_;

    char* ws = (char*)d_ws;
    size_t o = 0;
    float* target = (float*)(ws + o); o += (size_t)B_ * DIM_ * 4;       // 256 KB
    float* attnf  = (float*)(ws + o); o += (size_t)B_ * S_ * 4;         // 128 KB
    float* wc     = (float*)(ws + o); o += (size_t)B_ * DIM_ * 4;       // 256 KB
    float* gxall  = (float*)(ws + o); o += (size_t)B_ * TC_ * 4;        // 192 KB
    float* watt   = (float*)(ws + o); o += 4096;
    float* mvec   = (float*)(ws + o); o += (size_t)B_ * COV_ * 4;       // 64 KB
    float* bct    = (float*)(ws + o); o += 1024;
    float* bfold  = (float*)(ws + o); o += 4096;
    float* wfold  = (float*)(ws + o); o += (size_t)COV_ * TC_ * 4;      // 768 KB
    ushort_t* w_t    = (ushort_t*)(ws + o); o += (size_t)DIM_ * TC_ * 2;  // 1.5 MB
    ushort_t* whh_t  = (ushort_t*)(ws + o); o += (size_t)COV_ * TC_ * 2;  // 384 KB
    ushort_t* wcov_t = (ushort_t*)(ws + o); o += (size_t)COV_ * DIM_ * 2; // 512 KB
    int* flags = (int*)(ws + o); o += 256;
    // total ~4.1 MB

    // dtype detection first
    k_detect<<<1, 256, 0, stream>>>((const unsigned char*)maskp, (const ushort_t*)W_in, flags);

    // weight prep (canonical bf16 transposes + f32 folds)
    k_transpose<<<(TC_ * DIM_) / 256, 256, 0, stream>>>(w_ih, w_t, TC_, DIM_, KIH_, 0, flags);
    k_transpose<<<(TC_ * COV_) / 256, 256, 0, stream>>>(w_hh, whh_t, TC_, COV_, COV_, 0, flags);
    k_transpose<<<(DIM_ * COV_) / 256, 256, 0, stream>>>(W_cov, wcov_t, DIM_, COV_, COV_, 0, flags);
    k_watt<<<1, TC_, 0, stream>>>(w_ih, watt, flags);
    k_bfold<<<TC_ / 4, 256, 0, stream>>>(b_cov, w_ih, bfold, flags);
    k_wfold<<<COV_, 256, 0, stream>>>(wcov_t, w_t, wfold);

    // attention path
    k_target_w<<<(B_ * DIM_) / 4, 256, 0, stream>>>(h, W_in, target, flags);
    k_mvec<<<B_, 256, 0, stream>>>(target, W_cov, b_cov, mvec, bct, flags);
    k_scores_f<<<B_, 256, 0, stream>>>(context, cov, target, mvec, bct, maskp, flags,
                                       attnf, out_attn);
    k_wc_f<<<B_, 256, 0, stream>>>(context, cov, wcov_t, b_cov, attnf, wc, flags);
    k_htilde_w<<<(B_ * DIM_) / 4, 256, 0, stream>>>(wc, h, W_out, out_ht, flags);

    // GRU coverage path
    k_gxh_w<<<(B_ * TC_) / 4, 256, 0, stream>>>(h, w_ih, b_ih, bfold, gxall, flags);
    k_gru_f<<<(B_ * S_) / 8, 256, 0, stream>>>(context, cov, attnf, gxall, watt,
                                               w_t, wfold, whh_t, b_hh, out_cov, flags);
}

// Round 5
// 869.374 us; speedup vs baseline: 3.3959x; 3.3959x over previous
//
#include <hip/hip_runtime.h>
#include <math.h>

typedef unsigned short ushort_t;
typedef __attribute__((ext_vector_type(8))) short short8;
typedef __attribute__((ext_vector_type(4))) float f32x4;

constexpr int B_ = 64, S_ = 512, DIM_ = 1024, COV_ = 256, TC_ = 768, KIH_ = 2049;
constexpr int NG_ = 1024, KG_ = 1280;  // gates GEMM: [32768 x KG] @ [KG x NG]

__device__ __forceinline__ float b2f(ushort_t u) {
    union { unsigned int i; float f; } v; v.i = ((unsigned int)u) << 16; return v.f;
}
__device__ __forceinline__ ushort_t f2b(float f) {
    unsigned int x = __float_as_uint(f);
    unsigned int r = x + 0x7fffu + ((x >> 16) & 1u);
    return (ushort_t)(r >> 16);
}
__device__ __forceinline__ float ldv(const float* p, size_t i) { return p[i]; }
__device__ __forceinline__ float ldv(const ushort_t* p, size_t i) { return b2f(p[i]); }

__device__ __forceinline__ float wave_reduce(float a) {
#pragma unroll
    for (int off = 32; off >= 1; off >>= 1) a += __shfl_down(a, off, 64);
    return a;
}

// ---- dtype detection: flags[0]=mask_is_bytes, flags[1]=inputs_are_f32 ---------
__global__ void k_detect(const unsigned char* __restrict__ mask,
                         const ushort_t* __restrict__ win,
                         int* __restrict__ flags) {
    __shared__ int red0[256];
    __shared__ int red1[256];
    int tid = threadIdx.x, mb = 0, f32 = 0;
    for (int i = tid; i < 32768; i += 256)
        if ((i & 3) != 0 && mask[i] != 0) mb = 1;
    for (int i = tid; i < 32768; i += 256) {
        ushort_t u = win[2 * i];
        if ((u & 0x7F80u) >= 0x4480u) f32 = 1;
    }
    red0[tid] = mb; red1[tid] = f32; __syncthreads();
    for (int st = 128; st >= 1; st >>= 1) {
        if (tid < st) { red0[tid] |= red0[tid + st]; red1[tid] |= red1[tid + st]; }
        __syncthreads();
    }
    if (tid == 0) { flags[0] = red0[0]; flags[1] = red1[0]; }
}

// ---- generic transpose -> canonical bf16: out[c*R+r] = in[r*ld+off+c] ---------
template <typename IT>
__device__ __forceinline__ void transpose_body(const IT* __restrict__ in,
                                               ushort_t* __restrict__ out,
                                               int R, int C, int ld, int off) {
    int idx = blockIdx.x * 256 + threadIdx.x;
    if (idx >= R * C) return;
    int r = idx / C, c = idx - r * C;
    out[c * R + r] = f2b(ldv(in, (size_t)r * ld + off + c));
}
__global__ void k_transpose(const void* __restrict__ in, ushort_t* __restrict__ out,
                            int R, int C, int ld, int off, const int* __restrict__ flags) {
    if (flags[1]) transpose_body((const float*)in, out, R, C, ld, off);
    else transpose_body((const ushort_t*)in, out, R, C, ld, off);
}

// ---- watt[j] = w_ih[j, 2048] --------------------------------------------------
template <typename IT>
__device__ __forceinline__ void watt_body(const IT* __restrict__ wih, float* __restrict__ watt) {
    int j = threadIdx.x;  // 768 threads
    watt[j] = ldv(wih, (size_t)j * KIH_ + 2048);
}
__global__ void k_watt(const void* __restrict__ wih, float* __restrict__ watt,
                       const int* __restrict__ flags) {
    if (flags[1]) watt_body((const float*)wih, watt);
    else watt_body((const ushort_t*)wih, watt);
}

// ---- bfold[j] = sum_d bcov[d] * w_ih[j, d] ------------------------------------
template <typename IT>
__device__ __forceinline__ void bfold_body(const IT* __restrict__ bcov,
                                           const IT* __restrict__ wih,
                                           float* __restrict__ bfold) {
    int j = blockIdx.x * 4 + (threadIdx.x >> 6);
    int lane = threadIdx.x & 63;
    const IT* wr = wih + (size_t)j * KIH_;
    float a = 0.f;
#pragma unroll
    for (int i = 0; i < 16; ++i) { int k = lane + 64 * i; a += ldv(bcov, k) * ldv(wr, k); }
    a = wave_reduce(a);
    if (lane == 0) bfold[j] = a;
}
__global__ __launch_bounds__(256) void k_bfold(const void* __restrict__ bcov,
                                               const void* __restrict__ wih,
                                               float* __restrict__ bfold,
                                               const int* __restrict__ flags) {
    if (flags[1]) bfold_body((const float*)bcov, (const float*)wih, bfold);
    else bfold_body((const ushort_t*)bcov, (const ushort_t*)wih, bfold);
}

// ---- wfold[c*768+j] = sum_d W_cov[d,c] * w_ih[j,d] ----------------------------
__global__ __launch_bounds__(256) void k_wfold(const ushort_t* __restrict__ wcov_t,
                                               const ushort_t* __restrict__ w_t,
                                               float* __restrict__ wfold) {
    __shared__ float col[DIM_];
    int c = blockIdx.x, tid = threadIdx.x;
    for (int d = tid; d < DIM_; d += 256) col[d] = b2f(wcov_t[c * DIM_ + d]);
    __syncthreads();
    float a0 = 0.f, a1 = 0.f, a2 = 0.f;
    for (int d = 0; d < DIM_; ++d) {
        float x = col[d];
        const ushort_t* wr = w_t + d * TC_;
        a0 += x * b2f(wr[tid]);
        a1 += x * b2f(wr[tid + 256]);
        a2 += x * b2f(wr[tid + 512]);
    }
    wfold[c * TC_ + tid] = a0;
    wfold[c * TC_ + tid + 256] = a1;
    wfold[c * TC_ + tid + 512] = a2;
}

// ---- build Wg_t [NG=1024 rows][KG=1280 cols] bf16 -----------------------------
// col j of G: j<256 R, 256..511 Z, 512..767 XN, 768..1023 HN
template <typename IT>
__device__ __forceinline__ void buildwg_body(const IT* __restrict__ wih,
                                             const IT* __restrict__ whh,
                                             const float* __restrict__ wfold,
                                             ushort_t* __restrict__ wg) {
    int idx = blockIdx.x * 256 + threadIdx.x;
    if (idx >= NG_ * KG_) return;
    int j = idx / KG_, k = idx - j * KG_;
    float v;
    if (k < DIM_) {
        v = (j < TC_) ? ldv(wih, (size_t)j * KIH_ + k) : 0.f;
    } else {
        int c = k - DIM_;
        if (j < 512)      v = wfold[c * TC_ + j] + ldv(whh, (size_t)j * COV_ + c);
        else if (j < 768) v = wfold[c * TC_ + j];
        else              v = ldv(whh, (size_t)(j - 256) * COV_ + c);  // hn row 512+(j-768)
    }
    wg[(size_t)j * KG_ + k] = f2b(v);
}
__global__ void k_buildwg(const void* __restrict__ wih, const void* __restrict__ whh,
                          const float* __restrict__ wfold, ushort_t* __restrict__ wg,
                          const int* __restrict__ flags) {
    if (flags[1]) buildwg_body((const float*)wih, (const float*)whh, wfold, wg);
    else buildwg_body((const ushort_t*)wih, (const ushort_t*)whh, wfold, wg);
}

// ---- target = h @ W_in^T (wave per output) ------------------------------------
template <typename IT>
__device__ __forceinline__ void target_body(const IT* __restrict__ h,
                                            const IT* __restrict__ W_in,
                                            float* __restrict__ target) {
    int o = blockIdx.x * 4 + (threadIdx.x >> 6);
    int lane = threadIdx.x & 63;
    int b = o >> 10, d = o & (DIM_ - 1);
    const IT* hr = h + (size_t)b * DIM_;
    const IT* wr = W_in + (size_t)d * DIM_;
    float a = 0.f;
#pragma unroll
    for (int j = 0; j < 16; ++j) { int k = lane + 64 * j; a += ldv(hr, k) * ldv(wr, k); }
    a = wave_reduce(a);
    if (lane == 0) target[o] = a;
}
__global__ __launch_bounds__(256) void k_target_w(const void* __restrict__ h,
                                                  const void* __restrict__ W_in,
                                                  float* __restrict__ target,
                                                  const int* __restrict__ flags) {
    if (flags[1]) target_body((const float*)h, (const float*)W_in, target);
    else target_body((const ushort_t*)h, (const ushort_t*)W_in, target);
}

// ---- mvec[b,c] = sum_d target[b,d]*W_cov[d,c];  bct[b] = sum_d target*b_cov ---
template <typename IT>
__device__ __forceinline__ void mvec_body(const float* __restrict__ target,
                                          const IT* __restrict__ W_cov,
                                          const IT* __restrict__ bcov,
                                          float* __restrict__ mvec,
                                          float* __restrict__ bct) {
    __shared__ float tg[DIM_];
    __shared__ float red[256];
    int b = blockIdx.x, tid = threadIdx.x;
    float pb = 0.f;
    for (int k = tid; k < DIM_; k += 256) {
        float t = target[b * DIM_ + k];
        tg[k] = t; pb += t * ldv(bcov, k);
    }
    red[tid] = pb; __syncthreads();
    for (int st = 128; st >= 1; st >>= 1) {
        if (tid < st) red[tid] += red[tid + st];
        __syncthreads();
    }
    float acc = 0.f;
    for (int d = 0; d < DIM_; ++d) acc += tg[d] * ldv(W_cov, (size_t)d * COV_ + tid);
    mvec[b * COV_ + tid] = acc;
    if (tid == 0) bct[b] = red[0];
}
__global__ __launch_bounds__(256) void k_mvec(const float* __restrict__ target,
                                              const void* __restrict__ W_cov,
                                              const void* __restrict__ bcov,
                                              float* __restrict__ mvec,
                                              float* __restrict__ bct,
                                              const int* __restrict__ flags) {
    if (flags[1]) mvec_body(target, (const float*)W_cov, (const float*)bcov, mvec, bct);
    else mvec_body(target, (const ushort_t*)W_cov, (const ushort_t*)bcov, mvec, bct);
}

// ---- raw scores: grid (B, 8); each wave 16 s-rows -----------------------------
template <typename IT>
__device__ __forceinline__ void scoreraw_body(const IT* __restrict__ context,
                                              const IT* __restrict__ cov,
                                              const float* __restrict__ target,
                                              const float* __restrict__ mvec,
                                              const float* __restrict__ bct,
                                              float* __restrict__ scf) {
    __shared__ float tg[DIM_];
    __shared__ float ms[COV_];
    int b = blockIdx.x, tid = threadIdx.x;
    for (int k = tid; k < DIM_; k += 256) tg[k] = target[b * DIM_ + k];
    if (tid < COV_) ms[tid] = mvec[b * COV_ + tid];
    float bc = bct[b];
    __syncthreads();
    int wave = tid >> 6, lane = tid & 63;
    int s0 = blockIdx.y * 64 + wave * 16;
    for (int i = 0; i < 16; ++i) {
        int s = s0 + i;
        size_t row = (size_t)(b * S_ + s);
        const IT* cr = context + row * DIM_;
        const IT* vr = cov + row * COV_;
        float a = 0.f;
#pragma unroll
        for (int j = 0; j < 16; ++j) { int d = lane + 64 * j; a += ldv(cr, d) * tg[d]; }
#pragma unroll
        for (int j = 0; j < 4; ++j) { int c = lane + 64 * j; a += ldv(vr, c) * ms[c]; }
        a = wave_reduce(a);
        if (lane == 0) scf[row] = a + bc;
    }
}
__global__ __launch_bounds__(256) void k_scoreraw(const void* __restrict__ context,
                                                  const void* __restrict__ cov,
                                                  const float* __restrict__ target,
                                                  const float* __restrict__ mvec,
                                                  const float* __restrict__ bct,
                                                  float* __restrict__ scf,
                                                  const int* __restrict__ flags) {
    if (flags[1]) scoreraw_body((const float*)context, (const float*)cov, target, mvec, bct, scf);
    else scoreraw_body((const ushort_t*)context, (const ushort_t*)cov, target, mvec, bct, scf);
}

// ---- masked softmax over scf --------------------------------------------------
__global__ __launch_bounds__(256) void k_softmax(const float* __restrict__ scf,
                                                 const void* __restrict__ maskp,
                                                 const int* __restrict__ flags,
                                                 float* __restrict__ attnf,
                                                 float* __restrict__ attn_out) {
    __shared__ float red[256];
    int b = blockIdx.x, tid = threadIdx.x;
    int mb = flags[0];
    int i0 = b * S_ + tid, i1 = i0 + 256;
    int m0 = mb ? (int)((const unsigned char*)maskp)[i0] : ((const int*)maskp)[i0];
    int m1 = mb ? (int)((const unsigned char*)maskp)[i1] : ((const int*)maskp)[i1];
    float s0 = m0 ? -INFINITY : scf[i0];
    float s1 = m1 ? -INFINITY : scf[i1];
    red[tid] = fmaxf(s0, s1); __syncthreads();
    for (int st = 128; st >= 1; st >>= 1) {
        if (tid < st) red[tid] = fmaxf(red[tid], red[tid + st]);
        __syncthreads();
    }
    float mx = red[0]; __syncthreads();
    float e0 = expf(s0 - mx), e1 = expf(s1 - mx);
    red[tid] = e0 + e1; __syncthreads();
    for (int st = 128; st >= 1; st >>= 1) {
        if (tid < st) red[tid] += red[tid + st];
        __syncthreads();
    }
    float inv = 1.0f / red[0];
    float a0 = e0 * inv, a1 = e1 * inv;
    attnf[i0] = a0; attnf[i1] = a1;
    attn_out[i0] = a0; attn_out[i1] = a1;
}

// ---- wc partials: grid (B, 8); block sums 64 s-rows ---------------------------
// wc8[(chunk*B + b)*DIM + d] ; ac8[(chunk*B + b)*COV + c]
template <typename IT>
__device__ __forceinline__ void wcpart_body(const IT* __restrict__ context,
                                            const IT* __restrict__ cov,
                                            const float* __restrict__ attnf,
                                            float* __restrict__ wc8,
                                            float* __restrict__ ac8) {
    __shared__ float at[64];
    int b = blockIdx.x, ch = blockIdx.y, tid = threadIdx.x;
    int s0 = ch * 64;
    if (tid < 64) at[tid] = attnf[b * S_ + s0 + tid];
    __syncthreads();
    float acv = 0.f;
    for (int s = 0; s < 64; ++s)
        acv += at[s] * ldv(cov, ((size_t)(b * S_ + s0 + s)) * COV_ + tid);
    ac8[((size_t)ch * B_ + b) * COV_ + tid] = acv;
    float acc[4] = {0.f, 0.f, 0.f, 0.f};
    for (int s = 0; s < 64; ++s) {
        float w = at[s];
        const IT* cr = context + ((size_t)(b * S_ + s0 + s)) * DIM_;
        acc[0] += w * ldv(cr, tid);
        acc[1] += w * ldv(cr, tid + 256);
        acc[2] += w * ldv(cr, tid + 512);
        acc[3] += w * ldv(cr, tid + 768);
    }
    size_t base = ((size_t)ch * B_ + b) * DIM_;
    for (int m = 0; m < 4; ++m) wc8[base + tid + 256 * m] = acc[m];
}
__global__ __launch_bounds__(256) void k_wcpart(const void* __restrict__ context,
                                                const void* __restrict__ cov,
                                                const float* __restrict__ attnf,
                                                float* __restrict__ wc8,
                                                float* __restrict__ ac8,
                                                const int* __restrict__ flags) {
    if (flags[1]) wcpart_body((const float*)context, (const float*)cov, attnf, wc8, ac8);
    else wcpart_body((const ushort_t*)context, (const ushort_t*)cov, attnf, wc8, ac8);
}

// ---- wc final: reduce partials + ac@W_cov^T + b_cov ---------------------------
template <typename IT>
__device__ __forceinline__ void wcfin_body(const float* __restrict__ wc8,
                                           const float* __restrict__ ac8,
                                           const ushort_t* __restrict__ wcov_t,
                                           const IT* __restrict__ bcov,
                                           float* __restrict__ wc) {
    __shared__ float ac[COV_];
    int b = blockIdx.x, tid = threadIdx.x;
    float a = 0.f;
    for (int ch = 0; ch < 8; ++ch) a += ac8[((size_t)ch * B_ + b) * COV_ + tid];
    ac[tid] = a;
    __syncthreads();
    float acc[4] = {0.f, 0.f, 0.f, 0.f};
    for (int ch = 0; ch < 8; ++ch) {
        size_t base = ((size_t)ch * B_ + b) * DIM_;
        for (int m = 0; m < 4; ++m) acc[m] += wc8[base + tid + 256 * m];
    }
    for (int c = 0; c < COV_; ++c) {
        float av = ac[c];
        const ushort_t* wr = wcov_t + c * DIM_;
        acc[0] += av * b2f(wr[tid]);
        acc[1] += av * b2f(wr[tid + 256]);
        acc[2] += av * b2f(wr[tid + 512]);
        acc[3] += av * b2f(wr[tid + 768]);
    }
    for (int m = 0; m < 4; ++m) {
        int d = tid + 256 * m;
        wc[b * DIM_ + d] = acc[m] + ldv(bcov, d);
    }
}
__global__ __launch_bounds__(256) void k_wcfin(const float* __restrict__ wc8,
                                               const float* __restrict__ ac8,
                                               const ushort_t* __restrict__ wcov_t,
                                               const void* __restrict__ bcov,
                                               float* __restrict__ wc,
                                               const int* __restrict__ flags) {
    if (flags[1]) wcfin_body(wc8, ac8, wcov_t, (const float*)bcov, wc);
    else wcfin_body(wc8, ac8, wcov_t, (const ushort_t*)bcov, wc);
}

// ---- h_tilde = tanh([wc, h] @ W_out^T) (wave per output) ----------------------
template <typename IT>
__device__ __forceinline__ void htilde_body(const float* __restrict__ wc,
                                            const IT* __restrict__ h,
                                            const IT* __restrict__ W_out,
                                            float* __restrict__ out_ht) {
    int o = blockIdx.x * 4 + (threadIdx.x >> 6);
    int lane = threadIdx.x & 63;
    int b = o >> 10, d = o & (DIM_ - 1);
    const float* wcr = wc + b * DIM_;
    const IT* hr = h + (size_t)b * DIM_;
    const IT* wr = W_out + (size_t)d * 2 * DIM_;
    float a = 0.f;
#pragma unroll
    for (int j = 0; j < 16; ++j) { int k = lane + 64 * j; a += wcr[k] * ldv(wr, k); }
#pragma unroll
    for (int j = 0; j < 16; ++j) { int k = lane + 64 * j; a += ldv(hr, k) * ldv(wr, DIM_ + k); }
    a = wave_reduce(a);
    if (lane == 0) out_ht[o] = tanhf(a);
}
__global__ __launch_bounds__(256) void k_htilde_w(const float* __restrict__ wc,
                                                  const void* __restrict__ h,
                                                  const void* __restrict__ W_out,
                                                  float* __restrict__ out_ht,
                                                  const int* __restrict__ flags) {
    if (flags[1]) htilde_body(wc, (const float*)h, (const float*)W_out, out_ht);
    else htilde_body(wc, (const ushort_t*)h, (const ushort_t*)W_out, out_ht);
}

// ---- gxall[b,j] = b_ih[j] + bfold[j] + sum_k h[b,k]*w_ih[j,1024+k] ------------
template <typename IT>
__device__ __forceinline__ void gxh_body(const IT* __restrict__ h,
                                         const IT* __restrict__ w_ih,
                                         const IT* __restrict__ b_ih,
                                         const float* __restrict__ bfold,
                                         float* __restrict__ gxall) {
    int o = blockIdx.x * 4 + (threadIdx.x >> 6);
    int lane = threadIdx.x & 63;
    int b = o / TC_, j = o - b * TC_;
    const IT* hr = h + (size_t)b * DIM_;
    const IT* wr = w_ih + (size_t)j * KIH_ + DIM_;
    float a = 0.f;
#pragma unroll
    for (int i = 0; i < 16; ++i) { int k = lane + 64 * i; a += ldv(hr, k) * ldv(wr, k); }
    a = wave_reduce(a);
    if (lane == 0) gxall[o] = a + ldv(b_ih, j) + bfold[j];
}
__global__ __launch_bounds__(256) void k_gxh_w(const void* __restrict__ h,
                                               const void* __restrict__ w_ih,
                                               const void* __restrict__ b_ih,
                                               const float* __restrict__ bfold,
                                               float* __restrict__ gxall,
                                               const int* __restrict__ flags) {
    if (flags[1]) gxh_body((const float*)h, (const float*)w_ih, (const float*)b_ih, bfold, gxall);
    else gxh_body((const ushort_t*)h, (const ushort_t*)w_ih, (const ushort_t*)b_ih, bfold, gxall);
}

// ---- MFMA gates GEMM: G[rows x 1024] = X[rows x 1280] @ Wg_t^T ----------------
// grid (rows/128, 8); block 256 = 4 waves (2x2), each wave 64x64 of 128x128 tile
template <typename IT>
__device__ __forceinline__ void gemm_body(const IT* __restrict__ context,
                                          const IT* __restrict__ cov,
                                          const ushort_t* __restrict__ wg,
                                          float* __restrict__ G, int row_off) {
    __shared__ __align__(16) ushort_t As[128 * 32];
    __shared__ __align__(16) ushort_t Bs[128 * 32];
    int tid = threadIdx.x;
    int row0 = blockIdx.x * 128;        // within chunk
    int grow0 = row_off + row0;         // global X row
    int n0 = blockIdx.y * 128;
    int wave = tid >> 6, lane = tid & 63;
    int wm = wave >> 1, wn = wave & 1;
    int half = lane >> 4, r16 = lane & 15;
    f32x4 acc[4][4];
#pragma unroll
    for (int i = 0; i < 4; ++i)
#pragma unroll
        for (int j = 0; j < 4; ++j) acc[i][j] = (f32x4){0.f, 0.f, 0.f, 0.f};
    for (int kt = 0; kt < KG_ / 32; ++kt) {
        int k0 = kt * 32;
        const IT* X; int ldx, kk0;
        if (k0 < DIM_) { X = context; ldx = DIM_; kk0 = k0; }
        else           { X = cov;     ldx = COV_; kk0 = k0 - DIM_; }
        for (int i = tid; i < 128 * 32; i += 256) {
            int r = i >> 5, kk = i & 31;
            As[i] = f2b(ldv(X, (size_t)(grow0 + r) * ldx + kk0 + kk));
        }
        for (int i = tid; i < 128 * 32; i += 256) {
            int n = i >> 5, kk = i & 31;
            Bs[i] = wg[(size_t)(n0 + n) * KG_ + k0 + kk];
        }
        __syncthreads();
        short8 a[4], b[4];
#pragma unroll
        for (int t = 0; t < 4; ++t)
            a[t] = *(const short8*)&As[(wm * 64 + t * 16 + r16) * 32 + half * 8];
#pragma unroll
        for (int t = 0; t < 4; ++t)
            b[t] = *(const short8*)&Bs[(wn * 64 + t * 16 + r16) * 32 + half * 8];
#pragma unroll
        for (int i = 0; i < 4; ++i)
#pragma unroll
            for (int j = 0; j < 4; ++j)
                acc[i][j] = __builtin_amdgcn_mfma_f32_16x16x32_bf16(a[i], b[j], acc[i][j], 0, 0, 0);
        __syncthreads();
    }
    // C/D layout: col = lane&15, row = (lane>>4)*4 + reg
#pragma unroll
    for (int i = 0; i < 4; ++i)
#pragma unroll
        for (int j = 0; j < 4; ++j) {
            int gr = row0 + wm * 64 + i * 16 + half * 4;
            int gc = n0 + wn * 64 + j * 16 + r16;
#pragma unroll
            for (int rg = 0; rg < 4; ++rg)
                G[(size_t)(gr + rg) * NG_ + gc] = acc[i][j][rg];
        }
}
__global__ __launch_bounds__(256) void k_gemm(const void* __restrict__ context,
                                              const void* __restrict__ cov,
                                              const ushort_t* __restrict__ wg,
                                              float* __restrict__ G, int row_off,
                                              const int* __restrict__ flags) {
    if (flags[1]) gemm_body((const float*)context, (const float*)cov, wg, G, row_off);
    else gemm_body((const ushort_t*)context, (const ushort_t*)cov, wg, G, row_off);
}

// ---- GRU activation: one block per row ----------------------------------------
template <typename IT>
__device__ __forceinline__ void act_body(const float* __restrict__ G,
                                         const IT* __restrict__ cov,
                                         const float* __restrict__ attnf,
                                         const float* __restrict__ gxall,
                                         const float* __restrict__ watt,
                                         const IT* __restrict__ bhh,
                                         float* __restrict__ out_cov, int row_off) {
    int lr = blockIdx.x;                 // row within chunk
    int row = row_off + lr;              // global row
    int b = row >> 9;
    int c = threadIdx.x;
    float at = attnf[row];
    size_t gb = (size_t)lr * NG_;
    float aR  = G[gb + c]       + gxall[b * TC_ + c]       + at * watt[c]       + ldv(bhh, c);
    float aZ  = G[gb + 256 + c] + gxall[b * TC_ + 256 + c] + at * watt[256 + c] + ldv(bhh, 256 + c);
    float aXN = G[gb + 512 + c] + gxall[b * TC_ + 512 + c] + at * watt[512 + c];
    float aHN = G[gb + 768 + c] + ldv(bhh, 512 + c);
    float r = 1.f / (1.f + expf(-aR));
    float z = 1.f / (1.f + expf(-aZ));
    float n = tanhf(aXN + r * aHN);
    float h0 = ldv(cov, (size_t)row * COV_ + c);
    out_cov[(size_t)row * COV_ + c] = (1.f - z) * n + z * h0;
}
__global__ __launch_bounds__(256) void k_act(const float* __restrict__ G,
                                             const void* __restrict__ cov,
                                             const float* __restrict__ attnf,
                                             const float* __restrict__ gxall,
                                             const float* __restrict__ watt,
                                             const void* __restrict__ bhh,
                                             float* __restrict__ out_cov, int row_off,
                                             const int* __restrict__ flags) {
    if (flags[1]) act_body(G, (const float*)cov, attnf, gxall, watt, (const float*)bhh,
                           out_cov, row_off);
    else act_body(G, (const ushort_t*)cov, attnf, gxall, watt, (const ushort_t*)bhh,
                  out_cov, row_off);
}

// ---- legacy GRU (fallback when ws too small) ----------------------------------
template <typename IT>
__device__ __forceinline__ void gru_body(const IT* __restrict__ context,
                                         const IT* __restrict__ cov,
                                         const float* __restrict__ attnf,
                                         const float* __restrict__ gxall,
                                         const float* __restrict__ watt,
                                         const ushort_t* __restrict__ w_t,
                                         const float* __restrict__ wfold,
                                         const ushort_t* __restrict__ whh_t,
                                         const IT* __restrict__ bhh,
                                         float* __restrict__ out_cov) {
    __shared__ float xc[8][DIM_];
    __shared__ float h0s[8][COV_];
    __shared__ float atn[8];
    int base = blockIdx.x * 8, tid = threadIdx.x;
    int b = base / S_;
    for (int i = tid; i < 8 * DIM_; i += 256)
        ((float*)xc)[i] = ldv(context, (size_t)base * DIM_ + i);
    for (int i = tid; i < 8 * COV_; i += 256)
        ((float*)h0s)[i] = ldv(cov, (size_t)base * COV_ + i);
    if (tid < 8) atn[tid] = attnf[base + tid];
    __syncthreads();
    int c = tid;
    float gxR = gxall[b * TC_ + c], gxZ = gxall[b * TC_ + 256 + c], gxN = gxall[b * TC_ + 512 + c];
    float bhR = ldv(bhh, c), bhZ = ldv(bhh, 256 + c), bhN = ldv(bhh, 512 + c);
    float waR = watt[c], waZ = watt[256 + c], waN = watt[512 + c];
    float aR[8], aZ[8], aXN[8], aHN[8];
#pragma unroll
    for (int g = 0; g < 8; ++g) {
        float a = atn[g];
        aR[g] = gxR + bhR + a * waR;
        aZ[g] = gxZ + bhZ + a * waZ;
        aXN[g] = gxN + a * waN;
        aHN[g] = bhN;
    }
    for (int k = 0; k < DIM_; ++k) {
        const ushort_t* row = w_t + k * TC_;
        float wr = b2f(row[c]), wz = b2f(row[256 + c]), wn = b2f(row[512 + c]);
#pragma unroll
        for (int g = 0; g < 8; ++g) {
            float x = xc[g][k];
            aR[g] += x * wr; aZ[g] += x * wz; aXN[g] += x * wn;
        }
    }
    for (int k = 0; k < COV_; ++k) {
        const float* row = wfold + k * TC_;
        float wr = row[c], wz = row[256 + c], wn = row[512 + c];
#pragma unroll
        for (int g = 0; g < 8; ++g) {
            float x = h0s[g][k];
            aR[g] += x * wr; aZ[g] += x * wz; aXN[g] += x * wn;
        }
    }
    for (int k = 0; k < COV_; ++k) {
        const ushort_t* row = whh_t + k * TC_;
        float wr = b2f(row[c]), wz = b2f(row[256 + c]), wn = b2f(row[512 + c]);
#pragma unroll
        for (int g = 0; g < 8; ++g) {
            float hh = h0s[g][k];
            aR[g] += hh * wr; aZ[g] += hh * wz; aHN[g] += hh * wn;
        }
    }
#pragma unroll
    for (int g = 0; g < 8; ++g) {
        float r = 1.f / (1.f + expf(-aR[g]));
        float z = 1.f / (1.f + expf(-aZ[g]));
        float n = tanhf(aXN[g] + r * aHN[g]);
        float h0c = h0s[g][c];
        out_cov[(size_t)(base + g) * COV_ + c] = (1.f - z) * n + z * h0c;
    }
}
__global__ __launch_bounds__(256) void k_gru_f(const void* __restrict__ context,
                                               const void* __restrict__ cov,
                                               const float* __restrict__ attnf,
                                               const float* __restrict__ gxall,
                                               const float* __restrict__ watt,
                                               const ushort_t* __restrict__ w_t,
                                               const float* __restrict__ wfold,
                                               const ushort_t* __restrict__ whh_t,
                                               const void* __restrict__ bhh,
                                               float* __restrict__ out_cov,
                                               const int* __restrict__ flags) {
    if (flags[1]) gru_body((const float*)context, (const float*)cov, attnf, gxall, watt,
                           w_t, wfold, whh_t, (const float*)bhh, out_cov);
    else gru_body((const ushort_t*)context, (const ushort_t*)cov, attnf, gxall, watt,
                  w_t, wfold, whh_t, (const ushort_t*)bhh, out_cov);
}

extern "C" void kernel_launch(void* const* d_in, const int* in_sizes, int n_in,
                              void* d_out, int out_size, void* d_ws, size_t ws_size,
                              hipStream_t stream) {
    const void* h       = d_in[0];
    const void* context = d_in[1];
    const void* cov     = d_in[2];
    const void* W_in    = d_in[3];
    const void* W_out   = d_in[4];
    const void* W_cov   = d_in[5];
    const void* b_cov   = d_in[6];
    const void* w_ih    = d_in[7];
    const void* w_hh    = d_in[8];
    const void* b_ih    = d_in[9];
    const void* b_hh    = d_in[10];
    const void* maskp   = d_in[11];

    float* out = (float*)d_out;
    float* out_ht   = out;
    float* out_attn = out + B_ * DIM_;
    float* out_cov  = out + B_ * DIM_ + B_ * S_;

    char* ws = (char*)d_ws;
    size_t o = 0;
    float* target = (float*)(ws + o); o += (size_t)B_ * DIM_ * 4;
    float* attnf  = (float*)(ws + o); o += (size_t)B_ * S_ * 4;
    float* wc     = (float*)(ws + o); o += (size_t)B_ * DIM_ * 4;
    float* gxall  = (float*)(ws + o); o += (size_t)B_ * TC_ * 4;
    float* watt   = (float*)(ws + o); o += 4096;
    float* mvec   = (float*)(ws + o); o += (size_t)B_ * COV_ * 4;
    float* bct    = (float*)(ws + o); o += 4096;
    float* bfold  = (float*)(ws + o); o += 4096;
    float* wfold  = (float*)(ws + o); o += (size_t)COV_ * TC_ * 4;
    ushort_t* w_t    = (ushort_t*)(ws + o); o += (size_t)DIM_ * TC_ * 2;
    ushort_t* whh_t  = (ushort_t*)(ws + o); o += (size_t)COV_ * TC_ * 2;
    ushort_t* wcov_t = (ushort_t*)(ws + o); o += (size_t)COV_ * DIM_ * 2;
    int* flags = (int*)(ws + o); o += 256;
    float* scf   = (float*)(ws + o); o += (size_t)B_ * S_ * 4;
    float* wc8   = (float*)(ws + o); o += (size_t)8 * B_ * DIM_ * 4;
    float* ac8   = (float*)(ws + o); o += (size_t)8 * B_ * COV_ * 4;
    ushort_t* wg = (ushort_t*)(ws + o); o += (size_t)NG_ * KG_ * 2;
    size_t fixed = o;
    float* G = (float*)(ws + o);

    const size_t TOTAL_ROWS = (size_t)B_ * S_;  // 32768
    int CH;
    if (ws_size >= fixed + TOTAL_ROWS * NG_ * 4)      CH = 32768;
    else if (ws_size >= fixed + (size_t)8192 * NG_ * 4) CH = 8192;
    else if (ws_size >= fixed + (size_t)2048 * NG_ * 4) CH = 2048;
    else CH = 0;  // legacy fallback

    // dtype detection + weight prep
    k_detect<<<1, 256, 0, stream>>>((const unsigned char*)maskp, (const ushort_t*)W_in, flags);
    k_transpose<<<(TC_ * DIM_) / 256, 256, 0, stream>>>(w_ih, w_t, TC_, DIM_, KIH_, 0, flags);
    k_transpose<<<(DIM_ * COV_) / 256, 256, 0, stream>>>(W_cov, wcov_t, DIM_, COV_, COV_, 0, flags);
    if (CH == 0)
        k_transpose<<<(TC_ * COV_) / 256, 256, 0, stream>>>(w_hh, whh_t, TC_, COV_, COV_, 0, flags);
    k_watt<<<1, TC_, 0, stream>>>(w_ih, watt, flags);
    k_bfold<<<TC_ / 4, 256, 0, stream>>>(b_cov, w_ih, bfold, flags);
    k_wfold<<<COV_, 256, 0, stream>>>(wcov_t, w_t, wfold);
    if (CH != 0)
        k_buildwg<<<(NG_ * KG_ + 255) / 256, 256, 0, stream>>>(w_ih, w_hh, wfold, wg, flags);

    // attention path
    k_target_w<<<(B_ * DIM_) / 4, 256, 0, stream>>>(h, W_in, target, flags);
    k_mvec<<<B_, 256, 0, stream>>>(target, W_cov, b_cov, mvec, bct, flags);
    k_scoreraw<<<dim3(B_, 8), 256, 0, stream>>>(context, cov, target, mvec, bct, scf, flags);
    k_softmax<<<B_, 256, 0, stream>>>(scf, maskp, flags, attnf, out_attn);
    k_wcpart<<<dim3(B_, 8), 256, 0, stream>>>(context, cov, attnf, wc8, ac8, flags);
    k_wcfin<<<B_, 256, 0, stream>>>(wc8, ac8, wcov_t, b_cov, wc, flags);
    k_htilde_w<<<(B_ * DIM_) / 4, 256, 0, stream>>>(wc, h, W_out, out_ht, flags);

    // GRU coverage path
    k_gxh_w<<<(B_ * TC_) / 4, 256, 0, stream>>>(h, w_ih, b_ih, bfold, gxall, flags);
    if (CH != 0) {
        for (int off = 0; off < (int)TOTAL_ROWS; off += CH) {
            k_gemm<<<dim3(CH / 128, NG_ / 128), 256, 0, stream>>>(context, cov, wg, G, off, flags);
            k_act<<<CH, 256, 0, stream>>>(G, cov, attnf, gxall, watt, b_hh, out_cov, off, flags);
        }
    } else {
        k_gru_f<<<(B_ * S_) / 8, 256, 0, stream>>>(context, cov, attnf, gxall, watt,
                                                   w_t, wfold, whh_t, b_hh, out_cov, flags);
    }
}

// Round 6
// 785.960 us; speedup vs baseline: 3.7563x; 1.1061x over previous
//
#include <hip/hip_runtime.h>
#include <math.h>

typedef unsigned short ushort_t;
typedef __attribute__((ext_vector_type(8))) short short8;
typedef __attribute__((ext_vector_type(4))) float f32x4;

constexpr int B_ = 64, S_ = 512, DIM_ = 1024, COV_ = 256, TC_ = 768, KIH_ = 2049;
constexpr int NG_ = 1024, KG_ = 1280;  // gates GEMM: [32768 x KG] @ [KG x NG]

__device__ __forceinline__ float b2f(ushort_t u) {
    union { unsigned int i; float f; } v; v.i = ((unsigned int)u) << 16; return v.f;
}
__device__ __forceinline__ ushort_t f2b(float f) {
    unsigned int x = __float_as_uint(f);
    unsigned int r = x + 0x7fffu + ((x >> 16) & 1u);
    return (ushort_t)(r >> 16);
}
__device__ __forceinline__ float ldv(const float* p, size_t i) { return p[i]; }
__device__ __forceinline__ float ldv(const ushort_t* p, size_t i) { return b2f(p[i]); }

__device__ __forceinline__ float wave_reduce(float a) {
#pragma unroll
    for (int off = 32; off >= 1; off >>= 1) a += __shfl_down(a, off, 64);
    return a;
}

// ---- dtype detection: flags[0]=mask_is_bytes, flags[1]=inputs_are_f32 ---------
__global__ void k_detect(const unsigned char* __restrict__ mask,
                         const ushort_t* __restrict__ win,
                         int* __restrict__ flags) {
    __shared__ int red0[256];
    __shared__ int red1[256];
    int tid = threadIdx.x, mb = 0, f32 = 0;
    for (int i = tid; i < 32768; i += 256)
        if ((i & 3) != 0 && mask[i] != 0) mb = 1;
    for (int i = tid; i < 32768; i += 256) {
        ushort_t u = win[2 * i];
        if ((u & 0x7F80u) >= 0x4480u) f32 = 1;
    }
    red0[tid] = mb; red1[tid] = f32; __syncthreads();
    for (int st = 128; st >= 1; st >>= 1) {
        if (tid < st) { red0[tid] |= red0[tid + st]; red1[tid] |= red1[tid + st]; }
        __syncthreads();
    }
    if (tid == 0) { flags[0] = red0[0]; flags[1] = red1[0]; }
}

// ---- f32 -> bf16 bulk convert (8 elems/thread); no-op when inputs are bf16 ----
__global__ __launch_bounds__(256) void k_cvt(const void* __restrict__ in,
                                             ushort_t* __restrict__ out, int n8,
                                             const int* __restrict__ flags) {
    if (!flags[1]) return;
    int i = blockIdx.x * 256 + threadIdx.x;
    if (i >= n8) return;
    const float* p = (const float*)in + (size_t)i * 8;
    float4 x = *(const float4*)p;
    float4 y = *(const float4*)(p + 4);
    short8 v;
    v[0] = (short)f2b(x.x); v[1] = (short)f2b(x.y);
    v[2] = (short)f2b(x.z); v[3] = (short)f2b(x.w);
    v[4] = (short)f2b(y.x); v[5] = (short)f2b(y.y);
    v[6] = (short)f2b(y.z); v[7] = (short)f2b(y.w);
    *(short8*)(out + (size_t)i * 8) = v;
}

// ---- generic transpose -> canonical bf16: out[c*R+r] = in[r*ld+off+c] ---------
template <typename IT>
__device__ __forceinline__ void transpose_body(const IT* __restrict__ in,
                                               ushort_t* __restrict__ out,
                                               int R, int C, int ld, int off) {
    int idx = blockIdx.x * 256 + threadIdx.x;
    if (idx >= R * C) return;
    int r = idx / C, c = idx - r * C;
    out[c * R + r] = f2b(ldv(in, (size_t)r * ld + off + c));
}
__global__ void k_transpose(const void* __restrict__ in, ushort_t* __restrict__ out,
                            int R, int C, int ld, int off, const int* __restrict__ flags) {
    if (flags[1]) transpose_body((const float*)in, out, R, C, ld, off);
    else transpose_body((const ushort_t*)in, out, R, C, ld, off);
}

// ---- watt[j] = w_ih[j, 2048] --------------------------------------------------
template <typename IT>
__device__ __forceinline__ void watt_body(const IT* __restrict__ wih, float* __restrict__ watt) {
    int j = threadIdx.x;  // 768 threads
    watt[j] = ldv(wih, (size_t)j * KIH_ + 2048);
}
__global__ void k_watt(const void* __restrict__ wih, float* __restrict__ watt,
                       const int* __restrict__ flags) {
    if (flags[1]) watt_body((const float*)wih, watt);
    else watt_body((const ushort_t*)wih, watt);
}

// ---- bfold[j] = sum_d bcov[d] * w_ih[j, d] ------------------------------------
template <typename IT>
__device__ __forceinline__ void bfold_body(const IT* __restrict__ bcov,
                                           const IT* __restrict__ wih,
                                           float* __restrict__ bfold) {
    int j = blockIdx.x * 4 + (threadIdx.x >> 6);
    int lane = threadIdx.x & 63;
    const IT* wr = wih + (size_t)j * KIH_;
    float a = 0.f;
#pragma unroll
    for (int i = 0; i < 16; ++i) { int k = lane + 64 * i; a += ldv(bcov, k) * ldv(wr, k); }
    a = wave_reduce(a);
    if (lane == 0) bfold[j] = a;
}
__global__ __launch_bounds__(256) void k_bfold(const void* __restrict__ bcov,
                                               const void* __restrict__ wih,
                                               float* __restrict__ bfold,
                                               const int* __restrict__ flags) {
    if (flags[1]) bfold_body((const float*)bcov, (const float*)wih, bfold);
    else bfold_body((const ushort_t*)bcov, (const ushort_t*)wih, bfold);
}

// ---- wfold[c*768+j] = sum_d W_cov[d,c] * w_ih[j,d] ----------------------------
__global__ __launch_bounds__(256) void k_wfold(const ushort_t* __restrict__ wcov_t,
                                               const ushort_t* __restrict__ w_t,
                                               float* __restrict__ wfold) {
    __shared__ float col[DIM_];
    int c = blockIdx.x, tid = threadIdx.x;
    for (int d = tid; d < DIM_; d += 256) col[d] = b2f(wcov_t[c * DIM_ + d]);
    __syncthreads();
    float a0 = 0.f, a1 = 0.f, a2 = 0.f;
    for (int d = 0; d < DIM_; ++d) {
        float x = col[d];
        const ushort_t* wr = w_t + d * TC_;
        a0 += x * b2f(wr[tid]);
        a1 += x * b2f(wr[tid + 256]);
        a2 += x * b2f(wr[tid + 512]);
    }
    wfold[c * TC_ + tid] = a0;
    wfold[c * TC_ + tid + 256] = a1;
    wfold[c * TC_ + tid + 512] = a2;
}

// ---- build Wg_t [NG=1024 rows][KG=1280 cols] bf16 -----------------------------
template <typename IT>
__device__ __forceinline__ void buildwg_body(const IT* __restrict__ wih,
                                             const IT* __restrict__ whh,
                                             const float* __restrict__ wfold,
                                             ushort_t* __restrict__ wg) {
    int idx = blockIdx.x * 256 + threadIdx.x;
    if (idx >= NG_ * KG_) return;
    int j = idx / KG_, k = idx - j * KG_;
    float v;
    if (k < DIM_) {
        v = (j < TC_) ? ldv(wih, (size_t)j * KIH_ + k) : 0.f;
    } else {
        int c = k - DIM_;
        if (j < 512)      v = wfold[c * TC_ + j] + ldv(whh, (size_t)j * COV_ + c);
        else if (j < 768) v = wfold[c * TC_ + j];
        else              v = ldv(whh, (size_t)(j - 256) * COV_ + c);
    }
    wg[(size_t)j * KG_ + k] = f2b(v);
}
__global__ void k_buildwg(const void* __restrict__ wih, const void* __restrict__ whh,
                          const float* __restrict__ wfold, ushort_t* __restrict__ wg,
                          const int* __restrict__ flags) {
    if (flags[1]) buildwg_body((const float*)wih, (const float*)whh, wfold, wg);
    else buildwg_body((const ushort_t*)wih, (const ushort_t*)whh, wfold, wg);
}

// ---- target = h @ W_in^T (wave per output) ------------------------------------
template <typename IT>
__device__ __forceinline__ void target_body(const IT* __restrict__ h,
                                            const IT* __restrict__ W_in,
                                            float* __restrict__ target) {
    int o = blockIdx.x * 4 + (threadIdx.x >> 6);
    int lane = threadIdx.x & 63;
    int b = o >> 10, d = o & (DIM_ - 1);
    const IT* hr = h + (size_t)b * DIM_;
    const IT* wr = W_in + (size_t)d * DIM_;
    float a = 0.f;
#pragma unroll
    for (int j = 0; j < 16; ++j) { int k = lane + 64 * j; a += ldv(hr, k) * ldv(wr, k); }
    a = wave_reduce(a);
    if (lane == 0) target[o] = a;
}
__global__ __launch_bounds__(256) void k_target_w(const void* __restrict__ h,
                                                  const void* __restrict__ W_in,
                                                  float* __restrict__ target,
                                                  const int* __restrict__ flags) {
    if (flags[1]) target_body((const float*)h, (const float*)W_in, target);
    else target_body((const ushort_t*)h, (const ushort_t*)W_in, target);
}

// ---- mvec[b,c] = sum_d target[b,d]*W_cov[d,c];  bct[b] = sum_d target*b_cov ---
template <typename IT>
__device__ __forceinline__ void mvec_body(const float* __restrict__ target,
                                          const IT* __restrict__ W_cov,
                                          const IT* __restrict__ bcov,
                                          float* __restrict__ mvec,
                                          float* __restrict__ bct) {
    __shared__ float tg[DIM_];
    __shared__ float red[256];
    int b = blockIdx.x, tid = threadIdx.x;
    float pb = 0.f;
    for (int k = tid; k < DIM_; k += 256) {
        float t = target[b * DIM_ + k];
        tg[k] = t; pb += t * ldv(bcov, k);
    }
    red[tid] = pb; __syncthreads();
    for (int st = 128; st >= 1; st >>= 1) {
        if (tid < st) red[tid] += red[tid + st];
        __syncthreads();
    }
    float acc = 0.f;
    for (int d = 0; d < DIM_; ++d) acc += tg[d] * ldv(W_cov, (size_t)d * COV_ + tid);
    mvec[b * COV_ + tid] = acc;
    if (tid == 0) bct[b] = red[0];
}
__global__ __launch_bounds__(256) void k_mvec(const float* __restrict__ target,
                                              const void* __restrict__ W_cov,
                                              const void* __restrict__ bcov,
                                              float* __restrict__ mvec,
                                              float* __restrict__ bct,
                                              const int* __restrict__ flags) {
    if (flags[1]) mvec_body(target, (const float*)W_cov, (const float*)bcov, mvec, bct);
    else mvec_body(target, (const ushort_t*)W_cov, (const ushort_t*)bcov, mvec, bct);
}

// ---- raw scores: grid (B, 8); each wave 16 s-rows (f32 inputs for precision) --
template <typename IT>
__device__ __forceinline__ void scoreraw_body(const IT* __restrict__ context,
                                              const IT* __restrict__ cov,
                                              const float* __restrict__ target,
                                              const float* __restrict__ mvec,
                                              const float* __restrict__ bct,
                                              float* __restrict__ scf) {
    __shared__ float tg[DIM_];
    __shared__ float ms[COV_];
    int b = blockIdx.x, tid = threadIdx.x;
    for (int k = tid; k < DIM_; k += 256) tg[k] = target[b * DIM_ + k];
    if (tid < COV_) ms[tid] = mvec[b * COV_ + tid];
    float bc = bct[b];
    __syncthreads();
    int wave = tid >> 6, lane = tid & 63;
    int s0 = blockIdx.y * 64 + wave * 16;
    for (int i = 0; i < 16; ++i) {
        int s = s0 + i;
        size_t row = (size_t)(b * S_ + s);
        const IT* cr = context + row * DIM_;
        const IT* vr = cov + row * COV_;
        float a = 0.f;
#pragma unroll
        for (int j = 0; j < 16; ++j) { int d = lane + 64 * j; a += ldv(cr, d) * tg[d]; }
#pragma unroll
        for (int j = 0; j < 4; ++j) { int c = lane + 64 * j; a += ldv(vr, c) * ms[c]; }
        a = wave_reduce(a);
        if (lane == 0) scf[row] = a + bc;
    }
}
__global__ __launch_bounds__(256) void k_scoreraw(const void* __restrict__ context,
                                                  const void* __restrict__ cov,
                                                  const float* __restrict__ target,
                                                  const float* __restrict__ mvec,
                                                  const float* __restrict__ bct,
                                                  float* __restrict__ scf,
                                                  const int* __restrict__ flags) {
    if (flags[1]) scoreraw_body((const float*)context, (const float*)cov, target, mvec, bct, scf);
    else scoreraw_body((const ushort_t*)context, (const ushort_t*)cov, target, mvec, bct, scf);
}

// ---- masked softmax over scf --------------------------------------------------
__global__ __launch_bounds__(256) void k_softmax(const float* __restrict__ scf,
                                                 const void* __restrict__ maskp,
                                                 const int* __restrict__ flags,
                                                 float* __restrict__ attnf,
                                                 float* __restrict__ attn_out) {
    __shared__ float red[256];
    int b = blockIdx.x, tid = threadIdx.x;
    int mb = flags[0];
    int i0 = b * S_ + tid, i1 = i0 + 256;
    int m0 = mb ? (int)((const unsigned char*)maskp)[i0] : ((const int*)maskp)[i0];
    int m1 = mb ? (int)((const unsigned char*)maskp)[i1] : ((const int*)maskp)[i1];
    float s0 = m0 ? -INFINITY : scf[i0];
    float s1 = m1 ? -INFINITY : scf[i1];
    red[tid] = fmaxf(s0, s1); __syncthreads();
    for (int st = 128; st >= 1; st >>= 1) {
        if (tid < st) red[tid] = fmaxf(red[tid], red[tid + st]);
        __syncthreads();
    }
    float mx = red[0]; __syncthreads();
    float e0 = expf(s0 - mx), e1 = expf(s1 - mx);
    red[tid] = e0 + e1; __syncthreads();
    for (int st = 128; st >= 1; st >>= 1) {
        if (tid < st) red[tid] += red[tid + st];
        __syncthreads();
    }
    float inv = 1.0f / red[0];
    float a0 = e0 * inv, a1 = e1 * inv;
    attnf[i0] = a0; attnf[i1] = a1;
    attn_out[i0] = a0; attn_out[i1] = a1;
}

// ---- wc partials (bf16 inputs): grid (B, 8); block sums 64 s-rows -------------
__global__ __launch_bounds__(256) void k_wcpart2(const ushort_t* __restrict__ ctx_bf,
                                                 const ushort_t* __restrict__ cov_bf,
                                                 const void* __restrict__ ctx_in,
                                                 const void* __restrict__ cov_in,
                                                 const float* __restrict__ attnf,
                                                 float* __restrict__ wc8,
                                                 float* __restrict__ ac8,
                                                 const int* __restrict__ flags) {
    const ushort_t* C = flags[1] ? ctx_bf : (const ushort_t*)ctx_in;
    const ushort_t* V = flags[1] ? cov_bf : (const ushort_t*)cov_in;
    __shared__ float at[64];
    int b = blockIdx.x, ch = blockIdx.y, tid = threadIdx.x;
    int s0 = ch * 64;
    if (tid < 64) at[tid] = attnf[b * S_ + s0 + tid];
    __syncthreads();
    float acv = 0.f;
    for (int s = 0; s < 64; ++s)
        acv += at[s] * b2f(V[((size_t)(b * S_ + s0 + s)) * COV_ + tid]);
    ac8[((size_t)ch * B_ + b) * COV_ + tid] = acv;
    float acc[4] = {0.f, 0.f, 0.f, 0.f};
    for (int s = 0; s < 64; ++s) {
        float w = at[s];
        const ushort_t* cr = C + ((size_t)(b * S_ + s0 + s)) * DIM_;
        acc[0] += w * b2f(cr[tid]);
        acc[1] += w * b2f(cr[tid + 256]);
        acc[2] += w * b2f(cr[tid + 512]);
        acc[3] += w * b2f(cr[tid + 768]);
    }
    size_t base = ((size_t)ch * B_ + b) * DIM_;
    for (int m = 0; m < 4; ++m) wc8[base + tid + 256 * m] = acc[m];
}

// ---- wc final: reduce partials + ac@W_cov^T + b_cov ---------------------------
template <typename IT>
__device__ __forceinline__ void wcfin_body(const float* __restrict__ wc8,
                                           const float* __restrict__ ac8,
                                           const ushort_t* __restrict__ wcov_t,
                                           const IT* __restrict__ bcov,
                                           float* __restrict__ wc) {
    __shared__ float ac[COV_];
    int b = blockIdx.x, tid = threadIdx.x;
    float a = 0.f;
    for (int ch = 0; ch < 8; ++ch) a += ac8[((size_t)ch * B_ + b) * COV_ + tid];
    ac[tid] = a;
    __syncthreads();
    float acc[4] = {0.f, 0.f, 0.f, 0.f};
    for (int ch = 0; ch < 8; ++ch) {
        size_t base = ((size_t)ch * B_ + b) * DIM_;
        for (int m = 0; m < 4; ++m) acc[m] += wc8[base + tid + 256 * m];
    }
    for (int c = 0; c < COV_; ++c) {
        float av = ac[c];
        const ushort_t* wr = wcov_t + c * DIM_;
        acc[0] += av * b2f(wr[tid]);
        acc[1] += av * b2f(wr[tid + 256]);
        acc[2] += av * b2f(wr[tid + 512]);
        acc[3] += av * b2f(wr[tid + 768]);
    }
    for (int m = 0; m < 4; ++m) {
        int d = tid + 256 * m;
        wc[b * DIM_ + d] = acc[m] + ldv(bcov, d);
    }
}
__global__ __launch_bounds__(256) void k_wcfin(const float* __restrict__ wc8,
                                               const float* __restrict__ ac8,
                                               const ushort_t* __restrict__ wcov_t,
                                               const void* __restrict__ bcov,
                                               float* __restrict__ wc,
                                               const int* __restrict__ flags) {
    if (flags[1]) wcfin_body(wc8, ac8, wcov_t, (const float*)bcov, wc);
    else wcfin_body(wc8, ac8, wcov_t, (const ushort_t*)bcov, wc);
}

// ---- h_tilde = tanh([wc, h] @ W_out^T) (wave per output) ----------------------
template <typename IT>
__device__ __forceinline__ void htilde_body(const float* __restrict__ wc,
                                            const IT* __restrict__ h,
                                            const IT* __restrict__ W_out,
                                            float* __restrict__ out_ht) {
    int o = blockIdx.x * 4 + (threadIdx.x >> 6);
    int lane = threadIdx.x & 63;
    int b = o >> 10, d = o & (DIM_ - 1);
    const float* wcr = wc + b * DIM_;
    const IT* hr = h + (size_t)b * DIM_;
    const IT* wr = W_out + (size_t)d * 2 * DIM_;
    float a = 0.f;
#pragma unroll
    for (int j = 0; j < 16; ++j) { int k = lane + 64 * j; a += wcr[k] * ldv(wr, k); }
#pragma unroll
    for (int j = 0; j < 16; ++j) { int k = lane + 64 * j; a += ldv(hr, k) * ldv(wr, DIM_ + k); }
    a = wave_reduce(a);
    if (lane == 0) out_ht[o] = tanhf(a);
}
__global__ __launch_bounds__(256) void k_htilde_w(const float* __restrict__ wc,
                                                  const void* __restrict__ h,
                                                  const void* __restrict__ W_out,
                                                  float* __restrict__ out_ht,
                                                  const int* __restrict__ flags) {
    if (flags[1]) htilde_body(wc, (const float*)h, (const float*)W_out, out_ht);
    else htilde_body(wc, (const ushort_t*)h, (const ushort_t*)W_out, out_ht);
}

// ---- gxall[b,j] = b_ih[j] + bfold[j] + sum_k h[b,k]*w_ih[j,1024+k] ------------
template <typename IT>
__device__ __forceinline__ void gxh_body(const IT* __restrict__ h,
                                         const IT* __restrict__ w_ih,
                                         const IT* __restrict__ b_ih,
                                         const float* __restrict__ bfold,
                                         float* __restrict__ gxall) {
    int o = blockIdx.x * 4 + (threadIdx.x >> 6);
    int lane = threadIdx.x & 63;
    int b = o / TC_, j = o - b * TC_;
    const IT* hr = h + (size_t)b * DIM_;
    const IT* wr = w_ih + (size_t)j * KIH_ + DIM_;
    float a = 0.f;
#pragma unroll
    for (int i = 0; i < 16; ++i) { int k = lane + 64 * i; a += ldv(hr, k) * ldv(wr, k); }
    a = wave_reduce(a);
    if (lane == 0) gxall[o] = a + ldv(b_ih, j) + bfold[j];
}
__global__ __launch_bounds__(256) void k_gxh_w(const void* __restrict__ h,
                                               const void* __restrict__ w_ih,
                                               const void* __restrict__ b_ih,
                                               const float* __restrict__ bfold,
                                               float* __restrict__ gxall,
                                               const int* __restrict__ flags) {
    if (flags[1]) gxh_body((const float*)h, (const float*)w_ih, (const float*)b_ih, bfold, gxall);
    else gxh_body((const ushort_t*)h, (const ushort_t*)w_ih, (const ushort_t*)b_ih, bfold, gxall);
}

// ---- MFMA gates GEMM v2: global_load_lds staging + bank-swizzle ---------------
// G[rows x 1024] = Xbf16[rows x 1280] @ Wg^T. grid (NG/128, CH/128); 4 waves 2x2.
__global__ __launch_bounds__(256) void k_gemm2(const ushort_t* __restrict__ ctx_bf,
                                               const ushort_t* __restrict__ cov_bf,
                                               const void* __restrict__ ctx_in,
                                               const void* __restrict__ cov_in,
                                               const ushort_t* __restrict__ wg,
                                               float* __restrict__ G, int row_off,
                                               const int* __restrict__ flags) {
    const ushort_t* Xc = flags[1] ? ctx_bf : (const ushort_t*)ctx_in;
    const ushort_t* Xv = flags[1] ? cov_bf : (const ushort_t*)cov_in;
    __shared__ __align__(16) ushort_t As[128 * 32];
    __shared__ __align__(16) ushort_t Bs[128 * 32];
    int tid = threadIdx.x;
    int n0 = blockIdx.x * 128;
    int row0 = blockIdx.y * 128;
    int grow0 = row_off + row0;
    int wave = tid >> 6, lane = tid & 63;
    int wm = wave >> 1, wn = wave & 1;
    int half = lane >> 4, r16 = lane & 15;

    // staging chunk geometry: physical 16B chunk c = wave*128 + j*64 + lane
    // row = c>>2, sec_phys = c&3, sec_logical = sec_phys ^ ((row>>1)&3)
    int c0 = wave * 128 + lane;
    int ra0 = (c0) >> 2, sa0 = ((c0) & 3) ^ ((ra0 >> 1) & 3);
    int c1 = c0 + 64;
    int ra1 = (c1) >> 2, sa1 = ((c1) & 3) ^ ((ra1 >> 1) & 3);

    f32x4 acc[4][4];
#pragma unroll
    for (int i = 0; i < 4; ++i)
#pragma unroll
        for (int j = 0; j < 4; ++j) acc[i][j] = (f32x4){0.f, 0.f, 0.f, 0.f};

    for (int kt = 0; kt < KG_ / 32; ++kt) {
        int k0 = kt * 32;
        const ushort_t* X; size_t ldx; int kk0;
        if (k0 < DIM_) { X = Xc; ldx = DIM_; kk0 = k0; }
        else           { X = Xv; ldx = COV_; kk0 = k0 - DIM_; }
        // A tile: 128 rows x 32 k, 512 chunks of 16B
        {
            const ushort_t* g0 = X + (size_t)(grow0 + ra0) * ldx + kk0 + sa0 * 8;
            const ushort_t* g1 = X + (size_t)(grow0 + ra1) * ldx + kk0 + sa1 * 8;
            __builtin_amdgcn_global_load_lds(
                (const __attribute__((address_space(1))) void*)g0,
                (__attribute__((address_space(3))) void*)(As + (size_t)(wave * 128) * 8), 16, 0, 0);
            __builtin_amdgcn_global_load_lds(
                (const __attribute__((address_space(1))) void*)g1,
                (__attribute__((address_space(3))) void*)(As + (size_t)(wave * 128 + 64) * 8), 16, 0, 0);
        }
        // B tile: 128 n-rows x 32 k
        {
            const ushort_t* g0 = wg + (size_t)(n0 + ra0) * KG_ + k0 + sa0 * 8;
            const ushort_t* g1 = wg + (size_t)(n0 + ra1) * KG_ + k0 + sa1 * 8;
            __builtin_amdgcn_global_load_lds(
                (const __attribute__((address_space(1))) void*)g0,
                (__attribute__((address_space(3))) void*)(Bs + (size_t)(wave * 128) * 8), 16, 0, 0);
            __builtin_amdgcn_global_load_lds(
                (const __attribute__((address_space(1))) void*)g1,
                (__attribute__((address_space(3))) void*)(Bs + (size_t)(wave * 128 + 64) * 8), 16, 0, 0);
        }
        __syncthreads();
        short8 a[4], b[4];
#pragma unroll
        for (int t = 0; t < 4; ++t) {
            int row = wm * 64 + t * 16 + r16;
            int sec = half ^ ((row >> 1) & 3);
            a[t] = *(const short8*)&As[row * 32 + sec * 8];
        }
#pragma unroll
        for (int t = 0; t < 4; ++t) {
            int row = wn * 64 + t * 16 + r16;
            int sec = half ^ ((row >> 1) & 3);
            b[t] = *(const short8*)&Bs[row * 32 + sec * 8];
        }
#pragma unroll
        for (int i = 0; i < 4; ++i)
#pragma unroll
            for (int j = 0; j < 4; ++j)
                acc[i][j] = __builtin_amdgcn_mfma_f32_16x16x32_bf16(a[i], b[j], acc[i][j], 0, 0, 0);
        __syncthreads();
    }
    // C/D layout: col = lane&15, row = (lane>>4)*4 + reg
#pragma unroll
    for (int i = 0; i < 4; ++i)
#pragma unroll
        for (int j = 0; j < 4; ++j) {
            int gr = row0 + wm * 64 + i * 16 + half * 4;
            int gc = n0 + wn * 64 + j * 16 + r16;
#pragma unroll
            for (int rg = 0; rg < 4; ++rg)
                G[(size_t)(gr + rg) * NG_ + gc] = acc[i][j][rg];
        }
}

// ---- GRU activation: one block per row ----------------------------------------
template <typename IT>
__device__ __forceinline__ void act_body(const float* __restrict__ G,
                                         const IT* __restrict__ cov,
                                         const float* __restrict__ attnf,
                                         const float* __restrict__ gxall,
                                         const float* __restrict__ watt,
                                         const IT* __restrict__ bhh,
                                         float* __restrict__ out_cov, int row_off) {
    int lr = blockIdx.x;
    int row = row_off + lr;
    int b = row >> 9;
    int c = threadIdx.x;
    float at = attnf[row];
    size_t gb = (size_t)lr * NG_;
    float aR  = G[gb + c]       + gxall[b * TC_ + c]       + at * watt[c]       + ldv(bhh, c);
    float aZ  = G[gb + 256 + c] + gxall[b * TC_ + 256 + c] + at * watt[256 + c] + ldv(bhh, 256 + c);
    float aXN = G[gb + 512 + c] + gxall[b * TC_ + 512 + c] + at * watt[512 + c];
    float aHN = G[gb + 768 + c] + ldv(bhh, 512 + c);
    float r = 1.f / (1.f + expf(-aR));
    float z = 1.f / (1.f + expf(-aZ));
    float n = tanhf(aXN + r * aHN);
    float h0 = ldv(cov, (size_t)row * COV_ + c);
    out_cov[(size_t)row * COV_ + c] = (1.f - z) * n + z * h0;
}
__global__ __launch_bounds__(256) void k_act(const float* __restrict__ G,
                                             const void* __restrict__ cov,
                                             const float* __restrict__ attnf,
                                             const float* __restrict__ gxall,
                                             const float* __restrict__ watt,
                                             const void* __restrict__ bhh,
                                             float* __restrict__ out_cov, int row_off,
                                             const int* __restrict__ flags) {
    if (flags[1]) act_body(G, (const float*)cov, attnf, gxall, watt, (const float*)bhh,
                           out_cov, row_off);
    else act_body(G, (const ushort_t*)cov, attnf, gxall, watt, (const ushort_t*)bhh,
                  out_cov, row_off);
}

// ---- legacy GRU (fallback when ws too small) ----------------------------------
template <typename IT>
__device__ __forceinline__ void gru_body(const IT* __restrict__ context,
                                         const IT* __restrict__ cov,
                                         const float* __restrict__ attnf,
                                         const float* __restrict__ gxall,
                                         const float* __restrict__ watt,
                                         const ushort_t* __restrict__ w_t,
                                         const float* __restrict__ wfold,
                                         const ushort_t* __restrict__ whh_t,
                                         const IT* __restrict__ bhh,
                                         float* __restrict__ out_cov) {
    __shared__ float xc[8][DIM_];
    __shared__ float h0s[8][COV_];
    __shared__ float atn[8];
    int base = blockIdx.x * 8, tid = threadIdx.x;
    int b = base / S_;
    for (int i = tid; i < 8 * DIM_; i += 256)
        ((float*)xc)[i] = ldv(context, (size_t)base * DIM_ + i);
    for (int i = tid; i < 8 * COV_; i += 256)
        ((float*)h0s)[i] = ldv(cov, (size_t)base * COV_ + i);
    if (tid < 8) atn[tid] = attnf[base + tid];
    __syncthreads();
    int c = tid;
    float gxR = gxall[b * TC_ + c], gxZ = gxall[b * TC_ + 256 + c], gxN = gxall[b * TC_ + 512 + c];
    float bhR = ldv(bhh, c), bhZ = ldv(bhh, 256 + c), bhN = ldv(bhh, 512 + c);
    float waR = watt[c], waZ = watt[256 + c], waN = watt[512 + c];
    float aR[8], aZ[8], aXN[8], aHN[8];
#pragma unroll
    for (int g = 0; g < 8; ++g) {
        float a = atn[g];
        aR[g] = gxR + bhR + a * waR;
        aZ[g] = gxZ + bhZ + a * waZ;
        aXN[g] = gxN + a * waN;
        aHN[g] = bhN;
    }
    for (int k = 0; k < DIM_; ++k) {
        const ushort_t* row = w_t + k * TC_;
        float wr = b2f(row[c]), wz = b2f(row[256 + c]), wn = b2f(row[512 + c]);
#pragma unroll
        for (int g = 0; g < 8; ++g) {
            float x = xc[g][k];
            aR[g] += x * wr; aZ[g] += x * wz; aXN[g] += x * wn;
        }
    }
    for (int k = 0; k < COV_; ++k) {
        const float* row = wfold + k * TC_;
        float wr = row[c], wz = row[256 + c], wn = row[512 + c];
#pragma unroll
        for (int g = 0; g < 8; ++g) {
            float x = h0s[g][k];
            aR[g] += x * wr; aZ[g] += x * wz; aXN[g] += x * wn;
        }
    }
    for (int k = 0; k < COV_; ++k) {
        const ushort_t* row = whh_t + k * TC_;
        float wr = b2f(row[c]), wz = b2f(row[256 + c]), wn = b2f(row[512 + c]);
#pragma unroll
        for (int g = 0; g < 8; ++g) {
            float hh = h0s[g][k];
            aR[g] += hh * wr; aZ[g] += hh * wz; aHN[g] += hh * wn;
        }
    }
#pragma unroll
    for (int g = 0; g < 8; ++g) {
        float r = 1.f / (1.f + expf(-aR[g]));
        float z = 1.f / (1.f + expf(-aZ[g]));
        float n = tanhf(aXN[g] + r * aHN[g]);
        float h0c = h0s[g][c];
        out_cov[(size_t)(base + g) * COV_ + c] = (1.f - z) * n + z * h0c;
    }
}
__global__ __launch_bounds__(256) void k_gru_f(const void* __restrict__ context,
                                               const void* __restrict__ cov,
                                               const float* __restrict__ attnf,
                                               const float* __restrict__ gxall,
                                               const float* __restrict__ watt,
                                               const ushort_t* __restrict__ w_t,
                                               const float* __restrict__ wfold,
                                               const ushort_t* __restrict__ whh_t,
                                               const void* __restrict__ bhh,
                                               float* __restrict__ out_cov,
                                               const int* __restrict__ flags) {
    if (flags[1]) gru_body((const float*)context, (const float*)cov, attnf, gxall, watt,
                           w_t, wfold, whh_t, (const float*)bhh, out_cov);
    else gru_body((const ushort_t*)context, (const ushort_t*)cov, attnf, gxall, watt,
                  w_t, wfold, whh_t, (const ushort_t*)bhh, out_cov);
}

extern "C" void kernel_launch(void* const* d_in, const int* in_sizes, int n_in,
                              void* d_out, int out_size, void* d_ws, size_t ws_size,
                              hipStream_t stream) {
    const void* h       = d_in[0];
    const void* context = d_in[1];
    const void* cov     = d_in[2];
    const void* W_in    = d_in[3];
    const void* W_out   = d_in[4];
    const void* W_cov   = d_in[5];
    const void* b_cov   = d_in[6];
    const void* w_ih    = d_in[7];
    const void* w_hh    = d_in[8];
    const void* b_ih    = d_in[9];
    const void* b_hh    = d_in[10];
    const void* maskp   = d_in[11];

    float* out = (float*)d_out;
    float* out_ht   = out;
    float* out_attn = out + B_ * DIM_;
    float* out_cov  = out + B_ * DIM_ + B_ * S_;

    char* ws = (char*)d_ws;
    size_t o = 0;
    float* target = (float*)(ws + o); o += (size_t)B_ * DIM_ * 4;
    float* attnf  = (float*)(ws + o); o += (size_t)B_ * S_ * 4;
    float* wc     = (float*)(ws + o); o += (size_t)B_ * DIM_ * 4;
    float* gxall  = (float*)(ws + o); o += (size_t)B_ * TC_ * 4;
    float* watt   = (float*)(ws + o); o += 4096;
    float* mvec   = (float*)(ws + o); o += (size_t)B_ * COV_ * 4;
    float* bct    = (float*)(ws + o); o += 4096;
    float* bfold  = (float*)(ws + o); o += 4096;
    float* wfold  = (float*)(ws + o); o += (size_t)COV_ * TC_ * 4;
    ushort_t* w_t    = (ushort_t*)(ws + o); o += (size_t)DIM_ * TC_ * 2;
    ushort_t* whh_t  = (ushort_t*)(ws + o); o += (size_t)COV_ * TC_ * 2;
    ushort_t* wcov_t = (ushort_t*)(ws + o); o += (size_t)COV_ * DIM_ * 2;
    int* flags = (int*)(ws + o); o += 256;
    float* scf   = (float*)(ws + o); o += (size_t)B_ * S_ * 4;
    float* wc8   = (float*)(ws + o); o += (size_t)8 * B_ * DIM_ * 4;
    float* ac8   = (float*)(ws + o); o += (size_t)8 * B_ * COV_ * 4;
    ushort_t* wg = (ushort_t*)(ws + o); o += (size_t)NG_ * KG_ * 2;
    ushort_t* ctx_bf = (ushort_t*)(ws + o); o += (size_t)B_ * S_ * DIM_ * 2;  // 67 MB
    ushort_t* cov_bf = (ushort_t*)(ws + o); o += (size_t)B_ * S_ * COV_ * 2;  // 17 MB
    size_t fixed = o;
    float* G = (float*)(ws + o);

    const size_t TOTAL_ROWS = (size_t)B_ * S_;  // 32768
    int CH;
    if (ws_size >= fixed + TOTAL_ROWS * NG_ * 4)        CH = 32768;
    else if (ws_size >= fixed + (size_t)8192 * NG_ * 4) CH = 8192;
    else if (ws_size >= fixed + (size_t)2048 * NG_ * 4) CH = 2048;
    else CH = 0;  // legacy fallback

    // dtype detection + bf16 conversion + weight prep
    k_detect<<<1, 256, 0, stream>>>((const unsigned char*)maskp, (const ushort_t*)W_in, flags);
    if (CH != 0) {
        int n8c = (B_ * S_ * DIM_) / 8, n8v = (B_ * S_ * COV_) / 8;
        k_cvt<<<(n8c + 255) / 256, 256, 0, stream>>>(context, ctx_bf, n8c, flags);
        k_cvt<<<(n8v + 255) / 256, 256, 0, stream>>>(cov, cov_bf, n8v, flags);
    }
    k_transpose<<<(TC_ * DIM_) / 256, 256, 0, stream>>>(w_ih, w_t, TC_, DIM_, KIH_, 0, flags);
    k_transpose<<<(DIM_ * COV_) / 256, 256, 0, stream>>>(W_cov, wcov_t, DIM_, COV_, COV_, 0, flags);
    if (CH == 0)
        k_transpose<<<(TC_ * COV_) / 256, 256, 0, stream>>>(w_hh, whh_t, TC_, COV_, COV_, 0, flags);
    k_watt<<<1, TC_, 0, stream>>>(w_ih, watt, flags);
    k_bfold<<<TC_ / 4, 256, 0, stream>>>(b_cov, w_ih, bfold, flags);
    k_wfold<<<COV_, 256, 0, stream>>>(wcov_t, w_t, wfold);
    if (CH != 0)
        k_buildwg<<<(NG_ * KG_ + 255) / 256, 256, 0, stream>>>(w_ih, w_hh, wfold, wg, flags);

    // attention path
    k_target_w<<<(B_ * DIM_) / 4, 256, 0, stream>>>(h, W_in, target, flags);
    k_mvec<<<B_, 256, 0, stream>>>(target, W_cov, b_cov, mvec, bct, flags);
    k_scoreraw<<<dim3(B_, 8), 256, 0, stream>>>(context, cov, target, mvec, bct, scf, flags);
    k_softmax<<<B_, 256, 0, stream>>>(scf, maskp, flags, attnf, out_attn);
    if (CH != 0)
        k_wcpart2<<<dim3(B_, 8), 256, 0, stream>>>(ctx_bf, cov_bf, context, cov, attnf,
                                                   wc8, ac8, flags);
    else
        k_wcpart2<<<dim3(B_, 8), 256, 0, stream>>>((const ushort_t*)context, (const ushort_t*)cov,
                                                   context, cov, attnf, wc8, ac8, flags);
    k_wcfin<<<B_, 256, 0, stream>>>(wc8, ac8, wcov_t, b_cov, wc, flags);
    k_htilde_w<<<(B_ * DIM_) / 4, 256, 0, stream>>>(wc, h, W_out, out_ht, flags);

    // GRU coverage path
    k_gxh_w<<<(B_ * TC_) / 4, 256, 0, stream>>>(h, w_ih, b_ih, bfold, gxall, flags);
    if (CH != 0) {
        for (int off = 0; off < (int)TOTAL_ROWS; off += CH) {
            k_gemm2<<<dim3(NG_ / 128, CH / 128), 256, 0, stream>>>(ctx_bf, cov_bf, context, cov,
                                                                   wg, G, off, flags);
            k_act<<<CH, 256, 0, stream>>>(G, cov, attnf, gxall, watt, b_hh, out_cov, off, flags);
        }
    } else {
        k_gru_f<<<(B_ * S_) / 8, 256, 0, stream>>>(context, cov, attnf, gxall, watt,
                                                   w_t, wfold, whh_t, b_hh, out_cov, flags);
    }
}